// Round 4
// baseline (92.570 us; speedup 1.0000x reference)
//
#include <hip/hip_runtime.h>
#include <math.h>

#define LMAX 30.0f
typedef unsigned long long ull;

__device__ __forceinline__ float clip30(float x) { return fminf(fmaxf(x, -LMAX), LMAX); }
__device__ __forceinline__ float cnop(float x, float y) {
    x = clip30(x); y = clip30(y);
    const float m = fminf(fabsf(x), fabsf(y));
    const unsigned sg = (__float_as_uint(x) ^ __float_as_uint(y)) & 0x80000000u;
    return __uint_as_float(__float_as_uint(m) | sg);
}
__device__ __forceinline__ float splus(float z) {  // jax.nn.softplus, bit-exact form
    return fmaxf(z, 0.0f) + log1pf(expf(-fabsf(z)));
}
__device__ __forceinline__ ull bperm64b(ull v, int a) {  // a = byte addr (lane*4)
    const int lo = __builtin_amdgcn_ds_bpermute(a, (int)(unsigned)v);
    const int hi = __builtin_amdgcn_ds_bpermute(a, (int)(unsigned)(v >> 32));
    return ((ull)(unsigned)hi << 32) | (unsigned)lo;
}
__device__ __forceinline__ float gfb(float v, int a) {
    return __int_as_float(__builtin_amdgcn_ds_bpermute(a, __float_as_int(v)));
}

// ---- register-resident tree ----
// slot = lane&15, group p = lane>>4.
// seg5: S5[k] = seg5[p+4k] (k<8); seg4: S4[k] = seg4[p+4k] (k<4);
// seg3: S3[k] = seg3[p+4k] (k<2); seg2: R2[e] replicated; seg1: R1[e] replicated.
// ch6:  C[k] = ch6[p+4k] (k<16), so C[k+8] = ch6[(p+4k)+32].

#define F6_() { _Pragma("unroll") for (int k = 0; k < 8; ++k) S5[k] = cnop(C[k], C[k + 8]); }
#define G6_() { _Pragma("unroll") for (int k = 0; k < 8; ++k) { \
    const int u = (int)((uhw5 >> (p + 4 * k)) & 1ULL); \
    S5[k] = u ? (C[k + 8] - C[k]) : (C[k + 8] + C[k]); } }
#define F5_() { _Pragma("unroll") for (int k = 0; k < 4; ++k) S4[k] = cnop(S5[k], S5[k + 4]); }
#define G5_(II) { const int o = (II) - 80; _Pragma("unroll") for (int k = 0; k < 4; ++k) { \
    const int u = (int)((uhw4 >> (o + p + 4 * k)) & 1ULL); \
    S4[k] = u ? (S5[k + 4] - S5[k]) : (S5[k + 4] + S5[k]); } }
#define F4_() { _Pragma("unroll") for (int k = 0; k < 2; ++k) S3[k] = cnop(S4[k], S4[k + 2]); }
#define G4_(II) { const int o = (II) - 72; _Pragma("unroll") for (int k = 0; k < 2; ++k) { \
    const int u = (int)((uhw3 >> (o + p + 4 * k)) & 1ULL); \
    S3[k] = u ? (S4[k + 2] - S4[k]) : (S4[k + 2] + S4[k]); } }
// replicate one per-group value v0 = seg2[p] to R2[0..3] on every lane
#define REPL2(v0) { \
    const float t1_ = __shfl_xor((v0), 16); \
    const float lo_ = (p & 1) ? t1_ : (v0); \
    const float hi_ = (p & 1) ? (v0) : t1_; \
    const float lo2_ = __shfl_xor(lo_, 32); \
    const float hi2_ = __shfl_xor(hi_, 32); \
    R2[0] = (p < 2) ? lo_ : lo2_; R2[1] = (p < 2) ? hi_ : hi2_; \
    R2[2] = (p < 2) ? lo2_ : lo_; R2[3] = (p < 2) ? hi2_ : hi_; }
#define F3R_() { const float v0_ = cnop(S3[0], S3[1]); REPL2(v0_); }
#define G3R_(II) { const int o = (II) - 68; \
    const int u = (int)((uhw2 >> (o + p)) & 1ULL); \
    const float v0_ = u ? (S3[1] - S3[0]) : (S3[1] + S3[0]); REPL2(v0_); }
#define F2_() { R1[0] = cnop(R2[0], R2[2]); R1[1] = cnop(R2[1], R2[3]); }
#define G2_(II) { const int o = (II) - 66; \
    const int u0 = (int)((uhw1 >> o) & 1ULL), u1 = (int)((uhw1 >> (o + 1)) & 1ULL); \
    R1[0] = u0 ? (R2[2] - R2[0]) : (R2[2] + R2[0]); \
    R1[1] = u1 ? (R2[3] - R2[1]) : (R2[3] + R2[1]); }

#define COMBINE(sA, WA, WB) do { \
    const int h2 = 1 << ((sA) - 1); \
    const int o2 = (ii - (1 << (sA))) - 64; \
    const ull mh = (1ULL << h2) - 1ULL; \
    const ull ul = ((WA) >> o2) & mh; \
    const ull ur = ((WA) >> (o2 + h2)) & mh; \
    (WB) |= ((ul ^ ur) | (ur << h2)) << o2; \
} while (0)

// leaf: decision + pm + stable rank + (optional) clone of live state
#define LEAF_(II, L0, DOCLONE) { \
    const int u_ = (posR >= 8) ? 1 : 0; \
    if (u_) uhw0 |= (1ULL << ((II) - 64)); \
    const float l_ = clip30(L0); \
    pmR += splus(u_ ? l_ : -l_); \
    const unsigned pmB = __float_as_uint(pmR); \
    int r_ = 0; \
    _Pragma("unroll") \
    for (int j = 0; j < 16; ++j) { \
        const unsigned pmj = (unsigned)__builtin_amdgcn_readlane(__float_as_int(pmR), j); \
        const int posj = __builtin_amdgcn_readlane(posR, j); \
        r_ += ((pmj < pmB) || (pmj == pmB && posj < posR)) ? 1 : 0; \
    } \
    if (DOCLONE) { \
        const int P1_ = __builtin_amdgcn_ds_permute((r_ | base) << 2, slot); \
        const int up_ = __builtin_amdgcn_ds_bpermute((((r_ - 8) & 15) | base) << 2, P1_); \
        const int si_ = ((r_ >= 8) ? ((up_ & 15) | base) : lane) << 2; \
        pmR = gfb(pmR, si_); \
        uhw0 = bperm64b(uhw0, si_); \
        if (((II) >> 1) & 1) uhw1 = bperm64b(uhw1, si_); \
        if (((II) >> 2) & 1) uhw2 = bperm64b(uhw2, si_); \
        if (((II) >> 3) & 1) uhw3 = bperm64b(uhw3, si_); \
        if (((II) >> 4) & 1) uhw4 = bperm64b(uhw4, si_); \
        if (((II) & 1) == 0) { R1[0] = gfb(R1[0], si_); R1[1] = gfb(R1[1], si_); } \
        if ((((II) >> 1) & 1) == 0) { _Pragma("unroll") for (int e = 0; e < 4; ++e) R2[e] = gfb(R2[e], si_); } \
        if ((((II) >> 2) & 1) == 0) { _Pragma("unroll") for (int e = 0; e < 2; ++e) S3[e] = gfb(S3[e], si_); } \
        if ((((II) >> 3) & 1) == 0) { _Pragma("unroll") for (int e = 0; e < 4; ++e) S4[e] = gfb(S4[e], si_); } \
        if ((((II) >> 4) & 1) == 0) { _Pragma("unroll") for (int e = 0; e < 8; ++e) S5[e] = gfb(S5[e], si_); } \
    } \
    posR = r_; rR = r_; \
}

__global__ __launch_bounds__(64) void scl_kernel(const float* __restrict__ in,
                                                 float* __restrict__ out) {
    __shared__ float ch6[64];
    const int b = blockIdx.x;
    const int lane = threadIdx.x;
    const int slot = lane & 15;
    const int p = lane >> 4;
    const int base = lane & 48;

    const float a = -in[(size_t)b * 128 + lane];
    const float c = -in[(size_t)b * 128 + 64 + lane];
    ch6[lane] = a + c;   // stage-7 g with u=0 (frozen left subtree XOR == 0)
    __syncthreads();

    float C[16];
    #pragma unroll
    for (int k = 0; k < 16; ++k) C[k] = ch6[p + 4 * k];

    // ---- frozen half (leaves 0..63): paths identical, u == 0; butterfly
    float v = cnop(a, c);
    #pragma unroll
    for (int k = 5; k >= 0; --k) {
        const int h = 1 << k;
        const float o = __shfl_xor(v, h);
        v = (lane & h) ? (o + v) : cnop(v, o);
    }
    const float sp = splus(-clip30(v));
    float pmR = (slot == 0 || slot == 8) ? 0.0f : LMAX;
    #pragma unroll
    for (int j = 0; j < 64; ++j)
        pmR += __uint_as_float((unsigned)__builtin_amdgcn_readlane(__float_as_int(sp), j));

    int posR = slot;  // slot -> list position (replicated on all lanes)
    int rR = 0;
    float S5[8], S4[4], S3[2], R2[4], R1[2];
    ull uhw0 = 0, uhw1 = 0, uhw2 = 0, uhw3 = 0, uhw4 = 0, uhw5 = 0;

    // ---- info half (leaves 64..127) ----
    #pragma unroll 1
    for (int ie = 64; ie < 128; ie += 2) {
        {   // even leaf
            const int ii = ie;
            const int t = __builtin_ctz(ii);
            if (ii > 64) {
                COMBINE(1, uhw0, uhw1);
                if (t >= 2) COMBINE(2, uhw1, uhw2);
                if (t >= 3) COMBINE(3, uhw2, uhw3);
                if (t >= 4) COMBINE(4, uhw3, uhw4);
                if (t >= 5) COMBINE(5, uhw4, uhw5);
            }
            switch (t) {
                case 1: G2_(ii); break;
                case 2: G3R_(ii); F2_(); break;
                case 3: G4_(ii); F3R_(); F2_(); break;
                case 4: G5_(ii); F4_(); F3R_(); F2_(); break;
                case 5: G6_();    F5_(); F4_(); F3R_(); F2_(); break;
                default: F6_();   F5_(); F4_(); F3R_(); F2_(); break;  // ii == 64
            }
            const float l0 = cnop(R1[0], R1[1]);
            LEAF_(ii, l0, 1);
        }
        {   // odd leaf (t == 0): g at stage 1, fully local
            const int ii = ie + 1;
            const int ug = (int)((uhw0 >> (ii - 65)) & 1ULL);
            const float l0 = ug ? (R1[1] - R1[0]) : (R1[1] + R1[0]);
            LEAF_(ii, l0, (ii != 127));
        }
    }

    // best path = rank 0 (4 replica lanes have rR==0; take the first)
    const ull m = __ballot(rR == 0);
    const int bl = __builtin_ctzll(m);
    const unsigned wlo = (unsigned)__builtin_amdgcn_readlane((int)(unsigned)uhw0, bl);
    const unsigned whi = (unsigned)__builtin_amdgcn_readlane((int)(unsigned)(uhw0 >> 32), bl);
    const ull w = ((ull)whi << 32) | wlo;
    out[(size_t)b * 64 + lane] = (float)((w >> lane) & 1ULL);
}

extern "C" void kernel_launch(void* const* d_in, const int* in_sizes, int n_in,
                              void* d_out, int out_size, void* d_ws, size_t ws_size,
                              hipStream_t stream) {
    (void)n_in; (void)out_size; (void)d_ws; (void)ws_size;
    const float* in = (const float*)d_in[0];
    float* out = (float*)d_out;
    const int batch = in_sizes[0] / 128;  // 2048
    scl_kernel<<<dim3(batch), dim3(64), 0, stream>>>(in, out);
}

// Round 6
// 64.130 us; speedup vs baseline: 1.4435x; 1.4435x over previous
//
#include <hip/hip_runtime.h>
#include <math.h>

#define LMAX 30.0f
typedef unsigned long long ull;
typedef unsigned int u32;

__device__ __forceinline__ float clip30(float x) { return fminf(fmaxf(x, -LMAX), LMAX); }
__device__ __forceinline__ float cnop(float x, float y) {
    x = clip30(x); y = clip30(y);
    const float m = fminf(fabsf(x), fabsf(y));
    const unsigned sg = (__float_as_uint(x) ^ __float_as_uint(y)) & 0x80000000u;
    return __uint_as_float(__float_as_uint(m) | sg);
}

#define SWZI(x, PAT) __builtin_amdgcn_ds_swizzle((x), (PAT))
#define SWZF(x, PAT) __int_as_float(__builtin_amdgcn_ds_swizzle(__float_as_int(x), (PAT)))

// lane^32 partner via v_permlane32_swap (VALU, no DS).
#if __has_builtin(__builtin_amdgcn_permlane32_swap)
typedef int v2i_ __attribute__((ext_vector_type(2)));
__device__ __forceinline__ int swap32i(int x) {
    v2i_ r = __builtin_amdgcn_permlane32_swap(x, x, false, false);
    return (r[0] != x) ? r[0] : r[1];
}
#else
__device__ __forceinline__ int swap32i(int x) {
    int a = x, b = x;
    asm volatile("v_permlane32_swap_b32 %0, %1" : "+v"(a), "+v"(b));
    return (a != x) ? a : b;
}
#endif
__device__ __forceinline__ float swap32f(float x) {
    return __int_as_float(swap32i(__float_as_int(x)));
}
__device__ __forceinline__ float gfb(float v, int a) {
    return __int_as_float(__builtin_amdgcn_ds_bpermute(a, __float_as_int(v)));
}
__device__ __forceinline__ ull bperm64b(ull v, int a) {
    const int lo = __builtin_amdgcn_ds_bpermute(a, (int)(u32)v);
    const int hi = __builtin_amdgcn_ds_bpermute(a, (int)(u32)(v >> 32));
    return ((ull)(u32)hi << 32) | (u32)lo;
}

// polar encode (uhat derivation): pairwise (ul^ur | ur<<h) folds, h ascending
__device__ __forceinline__ u32 enc2(u32 w)  { w ^= (w >> 1) & 0x1u; return w; }
__device__ __forceinline__ u32 enc4(u32 w)  { w ^= (w >> 1) & 0x5u; w ^= (w >> 2) & 0x3u; return w; }
__device__ __forceinline__ u32 enc8(u32 w)  { w ^= (w >> 1) & 0x55u; w ^= (w >> 2) & 0x33u;
                                              w ^= (w >> 4) & 0x0fu; return w; }
__device__ __forceinline__ u32 enc16(u32 w) { w ^= (w >> 1) & 0x5555u; w ^= (w >> 2) & 0x3333u;
                                              w ^= (w >> 4) & 0x0f0fu; w ^= (w >> 8) & 0x00ffu; return w; }
__device__ __forceinline__ u32 enc32(u32 w) { w ^= (w >> 1) & 0x55555555u; w ^= (w >> 2) & 0x33333333u;
                                              w ^= (w >> 4) & 0x0f0f0f0fu; w ^= (w >> 8) & 0x00ff00ffu;
                                              w ^= (w >> 16) & 0x0000ffffu; return w; }

// ---- register tree, position-indexed. pos = lane&15, group p = lane>>4.
// seg5: S5[k]=seg5[p+4k] k<8; seg4: S4[k] k<4; seg3: S3[k] k<2;
// seg2: R2[0..3] replicated; seg1: R1[0..1] replicated; ch6: C[k]=ch6[p+4k] k<16.
#define F6_() { _Pragma("unroll") for (int k = 0; k < 8; ++k) S5[k] = cnop(C[k], C[k + 8]); }
#define G6_(II) { const u32 ub = enc32((u32)(uh >> ((II) - 96))); \
    _Pragma("unroll") for (int k = 0; k < 8; ++k) { \
        const int u = (ub >> (p + 4 * k)) & 1; \
        S5[k] = u ? (C[k + 8] - C[k]) : (C[k + 8] + C[k]); } }
#define F5_() { _Pragma("unroll") for (int k = 0; k < 4; ++k) S4[k] = cnop(S5[k], S5[k + 4]); }
#define G5_(II) { const u32 ub = enc16((u32)(uh >> ((II) - 80)) & 0xffffu); \
    _Pragma("unroll") for (int k = 0; k < 4; ++k) { \
        const int u = (ub >> (p + 4 * k)) & 1; \
        S4[k] = u ? (S5[k + 4] - S5[k]) : (S5[k + 4] + S5[k]); } }
#define F4_() { S3[0] = cnop(S4[0], S4[2]); S3[1] = cnop(S4[1], S4[3]); }
#define G4_(II) { const u32 ub = enc8((u32)(uh >> ((II) - 72)) & 0xffu); \
    _Pragma("unroll") for (int k = 0; k < 2; ++k) { \
        const int u = (ub >> (p + 4 * k)) & 1; \
        S3[k] = u ? (S4[k + 2] - S4[k]) : (S4[k + 2] + S4[k]); } }
#define REPL2(v0) { \
    const float t1_ = SWZF((v0), 0x401F); \
    const float lo_ = (p & 1) ? t1_ : (v0); \
    const float hi_ = (p & 1) ? (v0) : t1_; \
    const float lo2_ = swap32f(lo_); \
    const float hi2_ = swap32f(hi_); \
    R2[0] = (p < 2) ? lo_ : lo2_; R2[1] = (p < 2) ? hi_ : hi2_; \
    R2[2] = (p < 2) ? lo2_ : lo_; R2[3] = (p < 2) ? hi2_ : hi_; }
#define F3R_() { const float v0_ = cnop(S3[0], S3[1]); REPL2(v0_); }
#define G3R_(II) { const u32 ub = enc4((u32)(uh >> ((II) - 68)) & 0xfu); \
    const int u = (ub >> p) & 1; \
    const float v0_ = u ? (S3[1] - S3[0]) : (S3[1] + S3[0]); REPL2(v0_); }
#define F2_() { R1[0] = cnop(R2[0], R2[2]); R1[1] = cnop(R2[1], R2[3]); }
#define G2_(II) { const u32 ub = enc2((u32)(uh >> ((II) - 66)) & 3u); \
    R1[0] = (ub & 1) ? (R2[2] - R2[0]) : (R2[2] + R2[0]); \
    R1[1] = (ub & 2) ? (R2[3] - R2[1]) : (R2[3] + R2[1]); }

// leaf: decision + pm + distributed stable rank + invrank-gather relabel.
// Gather stays WITHIN the replica group -> distributed segs keep element alignment.
#define LEAF_(II, L0, DOCLONE) { \
    uh |= upBit << ((II) - 64); \
    const float l_ = clip30(L0); \
    const float tail_ = log1pf(expf(-fabsf(l_))); \
    pm += (isUp ? fmaxf(l_, 0.0f) : fmaxf(-l_, 0.0f)) + tail_; \
    int r_ = 0; \
    { \
        const u32 pmB = __float_as_uint(pm); \
        _Pragma("unroll") \
        for (int k = 0; k < 4; ++k) { \
            const u32 pmj = (u32)__builtin_amdgcn_ds_bpermute(A[k], __float_as_int(pm)); \
            r_ += ((pmj < pmB) || (pmj == pmB && (4 * p + k) < pos)) ? 1 : 0; \
        } \
    } \
    r_ += swap32i(r_); \
    r_ += SWZI(r_, 0x401F); \
    rFinal = r_; \
    if (DOCLONE) { \
        const int inv_ = __builtin_amdgcn_ds_permute((r_ | gbase) << 2, pos); \
        const int inv8_ = SWZI(inv_, 0x201F); \
        const int ga_ = (((lane & 8) ? inv8_ : inv_) | gbase) << 2; \
        pm = gfb(pm, ga_); \
        uh = bperm64b(uh, ga_); \
        if ((((II) >> 0) & 1) == 0) { R1[0] = gfb(R1[0], ga_); R1[1] = gfb(R1[1], ga_); } \
        if ((((II) >> 1) & 1) == 0) { _Pragma("unroll") for (int e = 0; e < 4; ++e) \
                                      R2[e] = gfb(R2[e], ga_); } \
        if ((((II) >> 2) & 1) == 0) { _Pragma("unroll") for (int e = 0; e < 2; ++e) \
                                      S3[e] = gfb(S3[e], ga_); } \
        if ((((II) >> 3) & 1) == 0) { _Pragma("unroll") for (int e = 0; e < 4; ++e) \
                                      S4[e] = gfb(S4[e], ga_); } \
        if ((((II) >> 4) & 1) == 0) { _Pragma("unroll") for (int e = 0; e < 8; ++e) \
                                      S5[e] = gfb(S5[e], ga_); } \
    } \
}

__global__ __launch_bounds__(64) void scl_kernel(const float* __restrict__ in,
                                                 float* __restrict__ out) {
    __shared__ float ch6s[64];
    const int b = blockIdx.x;
    const int lane = threadIdx.x;
    const int pos = lane & 15;                 // list position (fixed identity)
    const int p = lane >> 4;                   // replica group
    const int gbase = lane & 48;
    const bool isUp = (lane & 8) != 0;         // pos >= 8 -> u = 1
    const ull upBit = (ull)((lane >> 3) & 1);

    const float a = -in[(size_t)b * 128 + lane];
    const float c = -in[(size_t)b * 128 + 64 + lane];
    ch6s[lane] = a + c;                        // stage-6 llr of right subtree (u=0 g)
    __syncthreads();

    float C[16];
    #pragma unroll
    for (int k = 0; k < 16; ++k) C[k] = ch6s[p + 4 * k];

    // ---- frozen half (leaves 0..63): all paths identical, u == 0; butterfly
    float v = cnop(a, c);
    { const float o = swap32f(v);       v = (lane & 32) ? (o + v) : cnop(v, o); }
    { const float o = SWZF(v, 0x401F);  v = (lane & 16) ? (o + v) : cnop(v, o); }
    { const float o = SWZF(v, 0x201F);  v = (lane & 8)  ? (o + v) : cnop(v, o); }
    { const float o = SWZF(v, 0x101F);  v = (lane & 4)  ? (o + v) : cnop(v, o); }
    { const float o = SWZF(v, 0x081F);  v = (lane & 2)  ? (o + v) : cnop(v, o); }
    { const float o = SWZF(v, 0x041F);  v = (lane & 1)  ? (o + v) : cnop(v, o); }
    const float spf = fmaxf(-clip30(v), 0.0f) + log1pf(expf(-fabsf(clip30(v))));
    float pm = (pos == 0 || pos == 8) ? 0.0f : LMAX;
    #pragma unroll
    for (int j = 0; j < 64; ++j)
        pm += __uint_as_float((u32)__builtin_amdgcn_readlane(__float_as_int(spf), j));

    // rank-gather addresses: keys of positions 4p..4p+3, own group replicas
    int A[4];
    #pragma unroll
    for (int k = 0; k < 4; ++k) A[k] = ((4 * p + k) | gbase) << 2;

    float S5[8], S4[4], S3[2], R2[4], R1[2];
    ull uh = 0;
    int rFinal = 0;

    // ---- info half (leaves 64..127) ----
    #pragma unroll 1
    for (int ie = 64; ie < 128; ie += 2) {
        {   // even leaf
            const int ii = ie;
            const int t = __builtin_ctz(ii);
            switch (t) {
                case 1: { G2_(ii); } break;
                case 2: { G3R_(ii); F2_(); } break;
                case 3: { G4_(ii); F3R_(); F2_(); } break;
                case 4: { G5_(ii); F4_(); F3R_(); F2_(); } break;
                case 5: { G6_(ii); F5_(); F4_(); F3R_(); F2_(); } break;
                default: { F6_(); F5_(); F4_(); F3R_(); F2_(); } break;  // ii == 64
            }
            const float l0 = cnop(R1[0], R1[1]);
            LEAF_(ii, l0, 1);
        }
        {   // odd leaf (t == 0): stage-1 g, fully lane-local
            const int ii = ie + 1;
            const int ug = (int)((uh >> (ii - 65)) & 1ULL);
            const float l0 = ug ? (R1[1] - R1[0]) : (R1[1] + R1[0]);
            LEAF_(ii, l0, (ii != 127));
        }
    }

    // best path = rank 0 (4 replica lanes have rFinal==0; take the first)
    const ull m = __ballot(rFinal == 0);
    const int bl = (int)__builtin_ctzll(m);
    const u32 wlo = (u32)__builtin_amdgcn_readlane((int)(u32)uh, bl);
    const u32 whi = (u32)__builtin_amdgcn_readlane((int)(u32)(uh >> 32), bl);
    const ull w = ((ull)whi << 32) | wlo;
    out[(size_t)b * 64 + lane] = (float)((w >> lane) & 1ULL);
}

extern "C" void kernel_launch(void* const* d_in, const int* in_sizes, int n_in,
                              void* d_out, int out_size, void* d_ws, size_t ws_size,
                              hipStream_t stream) {
    (void)n_in; (void)out_size; (void)d_ws; (void)ws_size;
    const float* in = (const float*)d_in[0];
    float* out = (float*)d_out;
    const int batch = in_sizes[0] / 128;  // 2048
    scl_kernel<<<dim3(batch), dim3(64), 0, stream>>>(in, out);
}

// Round 7
// 64.022 us; speedup vs baseline: 1.4459x; 1.0017x over previous
//
#include <hip/hip_runtime.h>
#include <math.h>

#define LMAX 30.0f
typedef unsigned long long ull;
typedef unsigned int u32;

__device__ __forceinline__ float clip30(float x) { return fminf(fmaxf(x, -LMAX), LMAX); }
__device__ __forceinline__ float cnop(float x, float y) {
    x = clip30(x); y = clip30(y);
    const float m = fminf(fabsf(x), fabsf(y));
    const unsigned sg = (__float_as_uint(x) ^ __float_as_uint(y)) & 0x80000000u;
    return __uint_as_float(__float_as_uint(m) | sg);
}

#define SWZI(x, PAT) __builtin_amdgcn_ds_swizzle((x), (PAT))
#define SWZF(x, PAT) __int_as_float(__builtin_amdgcn_ds_swizzle(__float_as_int(x), (PAT)))

// DPP lane ops (VALU): ctrl must be ICE -> template param.
template<int CTRL>
__device__ __forceinline__ int dppi(int x) {
    return __builtin_amdgcn_update_dpp(x, x, CTRL, 0xF, 0xF, false);
}
template<int CTRL>
__device__ __forceinline__ float dppf(float x) {
    return __int_as_float(dppi<CTRL>(__float_as_int(x)));
}
// row_ror:8 == xor-8 within 16-lane rows (rotate by 8 in a 16-ring is an involution)
#define CTL_XOR8 0x128
#define CTL_XOR2 0x4E   /* quad_perm [2,3,0,1] */
#define CTL_XOR1 0xB1   /* quad_perm [1,0,3,2] */

// lane^32 partner via v_permlane32_swap (VALU).
#if __has_builtin(__builtin_amdgcn_permlane32_swap)
typedef int v2i_ __attribute__((ext_vector_type(2)));
__device__ __forceinline__ int swap32i(int x) {
    v2i_ r = __builtin_amdgcn_permlane32_swap(x, x, false, false);
    return (r[0] != x) ? r[0] : r[1];
}
#else
__device__ __forceinline__ int swap32i(int x) {
    int a = x, b = x;
    asm volatile("v_permlane32_swap_b32 %0, %1" : "+v"(a), "+v"(b));
    return (a != x) ? a : b;
}
#endif
// lane^16 partner via v_permlane16_swap (VALU); fallback: ds_swizzle xor-16.
#if __has_builtin(__builtin_amdgcn_permlane16_swap)
typedef int v2j_ __attribute__((ext_vector_type(2)));
__device__ __forceinline__ int swap16i(int x) {
    v2j_ r = __builtin_amdgcn_permlane16_swap(x, x, false, false);
    return (r[0] != x) ? r[0] : r[1];
}
#else
__device__ __forceinline__ int swap16i(int x) { return SWZI(x, 0x401F); }
#endif
__device__ __forceinline__ float swap32f(float x) { return __int_as_float(swap32i(__float_as_int(x))); }
__device__ __forceinline__ float swap16f(float x) { return __int_as_float(swap16i(__float_as_int(x))); }

__device__ __forceinline__ float gfb(float v, int a) {
    return __int_as_float(__builtin_amdgcn_ds_bpermute(a, __float_as_int(v)));
}
__device__ __forceinline__ ull bperm64b(ull v, int a) {
    const int lo = __builtin_amdgcn_ds_bpermute(a, (int)(u32)v);
    const int hi = __builtin_amdgcn_ds_bpermute(a, (int)(u32)(v >> 32));
    return ((ull)(u32)hi << 32) | (u32)lo;
}

// polar encode (uhat derivation): pairwise (ul^ur | ur<<h) folds, h ascending
__device__ __forceinline__ u32 enc2(u32 w)  { w ^= (w >> 1) & 0x1u; return w; }
__device__ __forceinline__ u32 enc4(u32 w)  { w ^= (w >> 1) & 0x5u; w ^= (w >> 2) & 0x3u; return w; }
__device__ __forceinline__ u32 enc8(u32 w)  { w ^= (w >> 1) & 0x55u; w ^= (w >> 2) & 0x33u;
                                              w ^= (w >> 4) & 0x0fu; return w; }
__device__ __forceinline__ u32 enc16(u32 w) { w ^= (w >> 1) & 0x5555u; w ^= (w >> 2) & 0x3333u;
                                              w ^= (w >> 4) & 0x0f0fu; w ^= (w >> 8) & 0x00ffu; return w; }
__device__ __forceinline__ u32 enc32(u32 w) { w ^= (w >> 1) & 0x55555555u; w ^= (w >> 2) & 0x33333333u;
                                              w ^= (w >> 4) & 0x0f0f0f0fu; w ^= (w >> 8) & 0x00ff00ffu;
                                              w ^= (w >> 16) & 0x0000ffffu; return w; }

// ---- register tree, position-indexed. pos = lane&15, group p = lane>>4.
// seg5: S5[k]=seg5[p+4k] k<8; seg4: S4[k] k<4; seg3: S3[k] k<2;
// seg2: R2[0..3] replicated; seg1: R1[0..1] replicated; ch6: C[k]=ch6[p+4k] k<16.
#define F6_() { _Pragma("unroll") for (int k = 0; k < 8; ++k) S5[k] = cnop(C[k], C[k + 8]); }
#define G6_(II) { const u32 ub = enc32((u32)(uh >> ((II) - 96))); \
    _Pragma("unroll") for (int k = 0; k < 8; ++k) { \
        const int u = (ub >> (p + 4 * k)) & 1; \
        S5[k] = u ? (C[k + 8] - C[k]) : (C[k + 8] + C[k]); } }
#define F5_() { _Pragma("unroll") for (int k = 0; k < 4; ++k) S4[k] = cnop(S5[k], S5[k + 4]); }
#define G5_(II) { const u32 ub = enc16((u32)(uh >> ((II) - 80)) & 0xffffu); \
    _Pragma("unroll") for (int k = 0; k < 4; ++k) { \
        const int u = (ub >> (p + 4 * k)) & 1; \
        S4[k] = u ? (S5[k + 4] - S5[k]) : (S5[k + 4] + S5[k]); } }
#define F4_() { S3[0] = cnop(S4[0], S4[2]); S3[1] = cnop(S4[1], S4[3]); }
#define G4_(II) { const u32 ub = enc8((u32)(uh >> ((II) - 72)) & 0xffu); \
    _Pragma("unroll") for (int k = 0; k < 2; ++k) { \
        const int u = (ub >> (p + 4 * k)) & 1; \
        S3[k] = u ? (S4[k + 2] - S4[k]) : (S4[k + 2] + S4[k]); } }
#define REPL2(v0) { \
    const float t1_ = swap16f(v0); \
    const float lo_ = (p & 1) ? t1_ : (v0); \
    const float hi_ = (p & 1) ? (v0) : t1_; \
    const float lo2_ = swap32f(lo_); \
    const float hi2_ = swap32f(hi_); \
    R2[0] = (p < 2) ? lo_ : lo2_; R2[1] = (p < 2) ? hi_ : hi2_; \
    R2[2] = (p < 2) ? lo2_ : lo_; R2[3] = (p < 2) ? hi2_ : hi_; }
#define F3R_() { const float v0_ = cnop(S3[0], S3[1]); REPL2(v0_); }
#define G3R_(II) { const u32 ub = enc4((u32)(uh >> ((II) - 68)) & 0xfu); \
    const int u = (ub >> p) & 1; \
    const float v0_ = u ? (S3[1] - S3[0]) : (S3[1] + S3[0]); REPL2(v0_); }
#define F2_() { R1[0] = cnop(R2[0], R2[2]); R1[1] = cnop(R2[1], R2[3]); }
#define G2_(II) { const u32 ub = enc2((u32)(uh >> ((II) - 66)) & 3u); \
    R1[0] = (ub & 1) ? (R2[2] - R2[0]) : (R2[2] + R2[0]); \
    R1[1] = (ub & 2) ? (R2[3] - R2[1]) : (R2[3] + R2[1]); }

// leaf: decision + pm + distributed stable rank (VALU reduce) + dual-scatter
// invrank + DPP xor-8 partner select + within-group clone gathers.
// DS chain depth: bpermute(rank) -> permute(scatter) -> gathers  (3 hops).
#define LEAF_(II, L0, DOCLONE) { \
    uh |= upBit << ((II) - 64); \
    const float l_ = clip30(L0); \
    const float tail_ = log1pf(expf(-fabsf(l_))); \
    pm += (isUp ? fmaxf(l_, 0.0f) : fmaxf(-l_, 0.0f)) + tail_; \
    int r_ = 0; \
    { \
        const u32 pmB = __float_as_uint(pm); \
        _Pragma("unroll") \
        for (int k = 0; k < 4; ++k) { \
            const u32 pmj = (u32)__builtin_amdgcn_ds_bpermute(A[k], __float_as_int(pm)); \
            r_ += ((pmj < pmB) || (pmj == pmB && (4 * p + k) < pos)) ? 1 : 0; \
        } \
    } \
    r_ += swap32i(r_); \
    r_ += swap16i(r_); \
    rFinal = r_; \
    if (DOCLONE) { \
        const int inv_ = __builtin_amdgcn_ds_permute(((r_ ^ swp8) | gbase) << 2, pos); \
        const int p8_ = dppi<CTL_XOR8>(inv_); \
        const int ga_ = ((needP ? p8_ : inv_) | gbase) << 2; \
        pm = gfb(pm, ga_); \
        uh = bperm64b(uh, ga_); \
        if ((((II) >> 0) & 1) == 0) { R1[0] = gfb(R1[0], ga_); R1[1] = gfb(R1[1], ga_); } \
        if ((((II) >> 1) & 1) == 0) { _Pragma("unroll") for (int e = 0; e < 4; ++e) \
                                      R2[e] = gfb(R2[e], ga_); } \
        if ((((II) >> 2) & 1) == 0) { _Pragma("unroll") for (int e = 0; e < 2; ++e) \
                                      S3[e] = gfb(S3[e], ga_); } \
        if ((((II) >> 3) & 1) == 0) { _Pragma("unroll") for (int e = 0; e < 4; ++e) \
                                      S4[e] = gfb(S4[e], ga_); } \
        if ((((II) >> 4) & 1) == 0) { _Pragma("unroll") for (int e = 0; e < 8; ++e) \
                                      S5[e] = gfb(S5[e], ga_); } \
    } \
}

__global__ __launch_bounds__(64) void scl_kernel(const float* __restrict__ in,
                                                 float* __restrict__ out) {
    __shared__ float ch6s[64];
    const int b = blockIdx.x;
    const int lane = threadIdx.x;
    const int pos = lane & 15;                 // list position (fixed identity)
    const int p = lane >> 4;                   // replica group (row of 16)
    const int gbase = lane & 48;
    const bool isUp = (lane & 8) != 0;         // pos >= 8 -> u = 1
    const ull upBit = (ull)((lane >> 3) & 1);
    const int swp8 = (lane & 32) >> 2;         // rows 2,3 scatter to r^8
    const bool needP = (((lane >> 3) ^ (lane >> 5)) & 1) != 0;

    const float a = -in[(size_t)b * 128 + lane];
    const float c = -in[(size_t)b * 128 + 64 + lane];
    ch6s[lane] = a + c;                        // stage-6 llr of right subtree (u=0 g)
    __syncthreads();

    float C[16];
    #pragma unroll
    for (int k = 0; k < 16; ++k) C[k] = ch6s[p + 4 * k];

    // ---- frozen half (leaves 0..63): all paths identical, u == 0; butterfly
    float v = cnop(a, c);
    { const float o = swap32f(v);            v = (lane & 32) ? (o + v) : cnop(v, o); }
    { const float o = swap16f(v);            v = (lane & 16) ? (o + v) : cnop(v, o); }
    { const float o = dppf<CTL_XOR8>(v);     v = (lane & 8)  ? (o + v) : cnop(v, o); }
    { const float o = SWZF(v, 0x101F);       v = (lane & 4)  ? (o + v) : cnop(v, o); }
    { const float o = dppf<CTL_XOR2>(v);     v = (lane & 2)  ? (o + v) : cnop(v, o); }
    { const float o = dppf<CTL_XOR1>(v);     v = (lane & 1)  ? (o + v) : cnop(v, o); }
    const float spf = fmaxf(-clip30(v), 0.0f) + log1pf(expf(-fabsf(clip30(v))));
    float pm = (pos == 0 || pos == 8) ? 0.0f : LMAX;
    #pragma unroll
    for (int j = 0; j < 64; ++j)
        pm += __uint_as_float((u32)__builtin_amdgcn_readlane(__float_as_int(spf), j));

    // rank-gather addresses: keys of positions 4p..4p+3, own row replicas
    int A[4];
    #pragma unroll
    for (int k = 0; k < 4; ++k) A[k] = ((4 * p + k) | gbase) << 2;

    float S5[8], S4[4], S3[2], R2[4], R1[2];
    ull uh = 0;
    int rFinal = 0;

    // ---- info half (leaves 64..127) ----
    #pragma unroll 1
    for (int ie = 64; ie < 128; ie += 2) {
        {   // even leaf
            const int ii = ie;
            const int t = __builtin_ctz(ii);
            switch (t) {
                case 1: { G2_(ii); } break;
                case 2: { G3R_(ii); F2_(); } break;
                case 3: { G4_(ii); F3R_(); F2_(); } break;
                case 4: { G5_(ii); F4_(); F3R_(); F2_(); } break;
                case 5: { G6_(ii); F5_(); F4_(); F3R_(); F2_(); } break;
                default: { F6_(); F5_(); F4_(); F3R_(); F2_(); } break;  // ii == 64
            }
            const float l0 = cnop(R1[0], R1[1]);
            LEAF_(ii, l0, 1);
        }
        {   // odd leaf (t == 0): stage-1 g, fully lane-local
            const int ii = ie + 1;
            const int ug = (int)((uh >> (ii - 65)) & 1ULL);
            const float l0 = ug ? (R1[1] - R1[0]) : (R1[1] + R1[0]);
            LEAF_(ii, l0, (ii != 127));
        }
    }

    // best path = rank 0 (4 replica lanes have rFinal==0; take the first)
    const ull m = __ballot(rFinal == 0);
    const int bl = (int)__builtin_ctzll(m);
    const u32 wlo = (u32)__builtin_amdgcn_readlane((int)(u32)uh, bl);
    const u32 whi = (u32)__builtin_amdgcn_readlane((int)(u32)(uh >> 32), bl);
    const ull w = ((ull)whi << 32) | wlo;
    out[(size_t)b * 64 + lane] = (float)((w >> lane) & 1ULL);
}

extern "C" void kernel_launch(void* const* d_in, const int* in_sizes, int n_in,
                              void* d_out, int out_size, void* d_ws, size_t ws_size,
                              hipStream_t stream) {
    (void)n_in; (void)out_size; (void)d_ws; (void)ws_size;
    const float* in = (const float*)d_in[0];
    float* out = (float*)d_out;
    const int batch = in_sizes[0] / 128;  // 2048
    scl_kernel<<<dim3(batch), dim3(64), 0, stream>>>(in, out);
}

// Round 8
// 62.347 us; speedup vs baseline: 1.4847x; 1.0269x over previous
//
#include <hip/hip_runtime.h>
#include <math.h>

#define LMAX 30.0f
typedef unsigned long long ull;
typedef unsigned int u32;

__device__ __forceinline__ float clip30(float x) { return fminf(fmaxf(x, -LMAX), LMAX); }
__device__ __forceinline__ float cnop(float x, float y) {
    x = clip30(x); y = clip30(y);
    const float m = fminf(fabsf(x), fabsf(y));
    const unsigned sg = (__float_as_uint(x) ^ __float_as_uint(y)) & 0x80000000u;
    return __uint_as_float(__float_as_uint(m) | sg);
}

#define SWZI(x, PAT) __builtin_amdgcn_ds_swizzle((x), (PAT))
#define SWZF(x, PAT) __int_as_float(__builtin_amdgcn_ds_swizzle(__float_as_int(x), (PAT)))

// DPP lane ops (VALU)
template<int CTRL>
__device__ __forceinline__ int dppi(int x) {
    return __builtin_amdgcn_update_dpp(x, x, CTRL, 0xF, 0xF, false);
}
template<int CTRL>
__device__ __forceinline__ float dppf(float x) {
    return __int_as_float(dppi<CTRL>(__float_as_int(x)));
}
#define CTL_XOR8 0x128  /* row_ror:8 == xor-8 within 16-lane rows */
#define CTL_XOR2 0x4E   /* quad_perm [2,3,0,1] */
#define CTL_XOR1 0xB1   /* quad_perm [1,0,3,2] */

// lane^16 partner via v_permlane16_swap (VALU); fallback ds_swizzle xor-16.
#if __has_builtin(__builtin_amdgcn_permlane16_swap)
typedef int v2j_ __attribute__((ext_vector_type(2)));
__device__ __forceinline__ int swap16i(int x) {
    v2j_ r = __builtin_amdgcn_permlane16_swap(x, x, false, false);
    return (r[0] != x) ? r[0] : r[1];
}
#else
__device__ __forceinline__ int swap16i(int x) { return SWZI(x, 0x401F); }
#endif
__device__ __forceinline__ float swap16f(float x) { return __int_as_float(swap16i(__float_as_int(x))); }

__device__ __forceinline__ float gfb(float v, int a) {
    return __int_as_float(__builtin_amdgcn_ds_bpermute(a, __float_as_int(v)));
}
__device__ __forceinline__ ull bperm64b(ull v, int a) {
    const int lo = __builtin_amdgcn_ds_bpermute(a, (int)(u32)v);
    const int hi = __builtin_amdgcn_ds_bpermute(a, (int)(u32)(v >> 32));
    return ((ull)(u32)hi << 32) | (u32)lo;
}

// polar encode (uhat derivation): pairwise (ul^ur | ur<<h) folds, h ascending
__device__ __forceinline__ u32 enc2(u32 w)  { w ^= (w >> 1) & 0x1u; return w; }
__device__ __forceinline__ u32 enc4(u32 w)  { w ^= (w >> 1) & 0x5u; w ^= (w >> 2) & 0x3u; return w; }
__device__ __forceinline__ u32 enc8(u32 w)  { w ^= (w >> 1) & 0x55u; w ^= (w >> 2) & 0x33u;
                                              w ^= (w >> 4) & 0x0fu; return w; }
__device__ __forceinline__ u32 enc16(u32 w) { w ^= (w >> 1) & 0x5555u; w ^= (w >> 2) & 0x3333u;
                                              w ^= (w >> 4) & 0x0f0fu; w ^= (w >> 8) & 0x00ffu; return w; }
__device__ __forceinline__ u32 enc32(u32 w) { w ^= (w >> 1) & 0x55555555u; w ^= (w >> 2) & 0x33333333u;
                                              w ^= (w >> 4) & 0x0f0f0f0fu; w ^= (w >> 8) & 0x00ff00ffu;
                                              w ^= (w >> 16) & 0x0000ffffu; return w; }

// ---- 2 decoders per wave. decoder d = lane>>5 (32 lanes each).
// Within decoder: pos = lane&15, row q = (lane>>4)&1.
// Distributed (stride 2 over rows): C[k]=ch6[q+2k] k<32; S5[k]=seg5[q+2k] k<16;
// S4[k]=seg4[q+2k] k<8; S3[k]=seg3[q+2k] k<4. Replicated per row: R2[4], R1[2].
#define F6_() { _Pragma("unroll") for (int k = 0; k < 16; ++k) S5[k] = cnop(C[k], C[k + 16]); }
#define G6_(II) { const u32 ub = enc32((u32)(uh >> ((II) - 96))); \
    _Pragma("unroll") for (int k = 0; k < 16; ++k) { \
        const int u = (ub >> (q + 2 * k)) & 1; \
        S5[k] = u ? (C[k + 16] - C[k]) : (C[k + 16] + C[k]); } }
#define F5_() { _Pragma("unroll") for (int k = 0; k < 8; ++k) S4[k] = cnop(S5[k], S5[k + 8]); }
#define G5_(II) { const u32 ub = enc16((u32)(uh >> ((II) - 80)) & 0xffffu); \
    _Pragma("unroll") for (int k = 0; k < 8; ++k) { \
        const int u = (ub >> (q + 2 * k)) & 1; \
        S4[k] = u ? (S5[k + 8] - S5[k]) : (S5[k + 8] + S5[k]); } }
#define F4_() { _Pragma("unroll") for (int k = 0; k < 4; ++k) S3[k] = cnop(S4[k], S4[k + 4]); }
#define G4_(II) { const u32 ub = enc8((u32)(uh >> ((II) - 72)) & 0xffu); \
    _Pragma("unroll") for (int k = 0; k < 4; ++k) { \
        const int u = (ub >> (q + 2 * k)) & 1; \
        S3[k] = u ? (S4[k + 4] - S4[k]) : (S4[k + 4] + S4[k]); } }
// replicate seg2 (row q holds elems q,q+2) to R2[0..3] on every lane
#define REPL2_(t0, t1) { \
    const float P0_ = swap16f(t0), P1_ = swap16f(t1); \
    R2[0] = q ? P0_ : (t0); R2[1] = q ? (t0) : P0_; \
    R2[2] = q ? P1_ : (t1); R2[3] = q ? (t1) : P1_; }
#define F3R_() { const float a0_ = cnop(S3[0], S3[2]); \
                 const float a1_ = cnop(S3[1], S3[3]); REPL2_(a0_, a1_); }
#define G3R_(II) { const u32 ub = enc4((u32)(uh >> ((II) - 68)) & 0xfu); \
    const int u0 = (ub >> q) & 1, u1 = (ub >> (q + 2)) & 1; \
    const float a0_ = u0 ? (S3[2] - S3[0]) : (S3[2] + S3[0]); \
    const float a1_ = u1 ? (S3[3] - S3[1]) : (S3[3] + S3[1]); REPL2_(a0_, a1_); }
#define F2_() { R1[0] = cnop(R2[0], R2[2]); R1[1] = cnop(R2[1], R2[3]); }
#define G2_(II) { const u32 ub = enc2((u32)(uh >> ((II) - 66)) & 3u); \
    R1[0] = (ub & 1) ? (R2[2] - R2[0]) : (R2[2] + R2[0]); \
    R1[1] = (ub & 2) ? (R2[3] - R2[1]) : (R2[3] + R2[1]); }

// leaf: decision + pm + distributed stable rank (8 keys/lane, swap16 reduce) +
// row-local invrank scatter + dpp xor-8 partner + within-row clone gathers.
#define LEAF_(II, L0, DOCLONE) { \
    uh |= upBit << ((II) - 64); \
    const float l_ = clip30(L0); \
    const float tail_ = log1pf(expf(-fabsf(l_))); \
    pm += (isUp ? fmaxf(l_, 0.0f) : fmaxf(-l_, 0.0f)) + tail_; \
    int r_ = 0; \
    { \
        const u32 pmB = __float_as_uint(pm); \
        _Pragma("unroll") \
        for (int k = 0; k < 8; ++k) { \
            const u32 pmj = (u32)__builtin_amdgcn_ds_bpermute(A0 + 4 * k, __float_as_int(pm)); \
            r_ += ((pmj < pmB) || (pmj == pmB && (idx0 + k) < pos)) ? 1 : 0; \
        } \
    } \
    r_ += swap16i(r_); \
    rFinal = r_; \
    if (DOCLONE) { \
        const int inv_ = __builtin_amdgcn_ds_permute((r_ | gbase) << 2, pos); \
        const int p8_ = dppi<CTL_XOR8>(inv_); \
        const int ga_ = ((isUp ? p8_ : inv_) | gbase) << 2; \
        pm = gfb(pm, ga_); \
        uh = bperm64b(uh, ga_); \
        if ((((II) >> 0) & 1) == 0) { R1[0] = gfb(R1[0], ga_); R1[1] = gfb(R1[1], ga_); } \
        if ((((II) >> 1) & 1) == 0) { _Pragma("unroll") for (int e = 0; e < 4; ++e) \
                                      R2[e] = gfb(R2[e], ga_); } \
        if ((((II) >> 2) & 1) == 0) { _Pragma("unroll") for (int e = 0; e < 4; ++e) \
                                      S3[e] = gfb(S3[e], ga_); } \
        if ((((II) >> 3) & 1) == 0) { _Pragma("unroll") for (int e = 0; e < 8; ++e) \
                                      S4[e] = gfb(S4[e], ga_); } \
        if ((((II) >> 4) & 1) == 0) { _Pragma("unroll") for (int e = 0; e < 16; ++e) \
                                      S5[e] = gfb(S5[e], ga_); } \
    } \
}

#define RLF(x, J) __uint_as_float((u32)__builtin_amdgcn_readlane(__float_as_int(x), (J)))

__global__ __launch_bounds__(64) void scl_kernel(const float* __restrict__ in,
                                                 float* __restrict__ out) {
    __shared__ float chS[128];
    const int lane = threadIdx.x;
    const int w = lane & 31;                   // within-decoder lane
    const int d = lane >> 5;                   // decoder (2 per wave)
    const int pos = lane & 15;                 // list position
    const int q = (lane >> 4) & 1;             // replica row within decoder
    const int gbase = lane & 48;               // decoder-row base
    const int dbase = lane & 32;               // decoder base
    const bool isUp = (lane & 8) != 0;         // pos >= 8 -> u = 1
    const ull upBit = (ull)((lane >> 3) & 1);
    const int idx0 = q << 3;                   // rank-compare index base
    const int A0 = (dbase | (q << 3)) << 2;    // rank-gather byte addr base

    const size_t base = ((size_t)blockIdx.x * 2 + d) * 128;
    const float a1 = -in[base + w],      c1 = -in[base + 64 + w];
    const float a2 = -in[base + 32 + w], c2 = -in[base + 96 + w];
    chS[d * 64 + w] = a1 + c1;                 // stage-6 right-subtree llr (u=0 g)
    chS[d * 64 + 32 + w] = a2 + c2;
    __syncthreads();
    float C[32];
    #pragma unroll
    for (int k = 0; k < 32; ++k) C[k] = chS[d * 64 + q + 2 * k];

    // ---- frozen half (leaves 0..63): paths identical, u == 0; butterfly.
    // Lane holds elems {w, w+32}; h=32 in-lane, h=16..1 cross-lane (in-decoder).
    float v1 = cnop(a1, c1), v2 = cnop(a2, c2);
    { const float n1 = cnop(v1, v2); v2 = v1 + v2; v1 = n1; }             // h=32
    { const float o1 = swap16f(v1), o2 = swap16f(v2);                      // h=16
      v1 = (w & 16) ? (o1 + v1) : cnop(v1, o1);
      v2 = (w & 16) ? (o2 + v2) : cnop(v2, o2); }
    { const float o1 = dppf<CTL_XOR8>(v1), o2 = dppf<CTL_XOR8>(v2);        // h=8
      v1 = (w & 8) ? (o1 + v1) : cnop(v1, o1);
      v2 = (w & 8) ? (o2 + v2) : cnop(v2, o2); }
    { const float o1 = SWZF(v1, 0x101F), o2 = SWZF(v2, 0x101F);            // h=4
      v1 = (w & 4) ? (o1 + v1) : cnop(v1, o1);
      v2 = (w & 4) ? (o2 + v2) : cnop(v2, o2); }
    { const float o1 = dppf<CTL_XOR2>(v1), o2 = dppf<CTL_XOR2>(v2);        // h=2
      v1 = (w & 2) ? (o1 + v1) : cnop(v1, o1);
      v2 = (w & 2) ? (o2 + v2) : cnop(v2, o2); }
    { const float o1 = dppf<CTL_XOR1>(v1), o2 = dppf<CTL_XOR1>(v2);        // h=1
      v1 = (w & 1) ? (o1 + v1) : cnop(v1, o1);
      v2 = (w & 1) ? (o2 + v2) : cnop(v2, o2); }
    const float sp1 = fmaxf(-clip30(v1), 0.0f) + log1pf(expf(-fabsf(clip30(v1))));
    const float sp2 = fmaxf(-clip30(v2), 0.0f) + log1pf(expf(-fabsf(clip30(v2))));

    // exact sequential pm accumulation per decoder (reference FP order)
    float pm = ((pos == 0) || (pos == 8)) ? 0.0f : LMAX;
    if (lane < 32) {
        #pragma unroll
        for (int j = 0; j < 32; ++j) pm += RLF(sp1, j);
        #pragma unroll
        for (int j = 0; j < 32; ++j) pm += RLF(sp2, j);
    } else {
        #pragma unroll
        for (int j = 32; j < 64; ++j) pm += RLF(sp1, j);
        #pragma unroll
        for (int j = 32; j < 64; ++j) pm += RLF(sp2, j);
    }

    float S5[16], S4[8], S3[4], R2[4], R1[2];
    ull uh = 0;
    int rFinal = 0;

    // ---- info half (leaves 64..127) ----
    #pragma unroll 1
    for (int ie = 64; ie < 128; ie += 2) {
        {   // even leaf
            const int ii = ie;
            const int t = __builtin_ctz(ii);
            switch (t) {
                case 1: { G2_(ii); } break;
                case 2: { G3R_(ii); F2_(); } break;
                case 3: { G4_(ii); F3R_(); F2_(); } break;
                case 4: { G5_(ii); F4_(); F3R_(); F2_(); } break;
                case 5: { G6_(ii); F5_(); F4_(); F3R_(); F2_(); } break;
                default: { F6_(); F5_(); F4_(); F3R_(); F2_(); } break;  // ii == 64
            }
            const float l0 = cnop(R1[0], R1[1]);
            LEAF_(ii, l0, 1);
        }
        {   // odd leaf (t == 0): stage-1 g, fully lane-local
            const int ii = ie + 1;
            const int ug = (int)((uh >> (ii - 65)) & 1ULL);
            const float l0 = ug ? (R1[1] - R1[0]) : (R1[1] + R1[0]);
            LEAF_(ii, l0, (ii != 127));
        }
    }

    // best path per decoder = rank 0; fetch its uh via per-lane bpermute
    const ull m = __ballot(rFinal == 0);
    const int bl = dbase + (int)__builtin_ctz((u32)(m >> dbase));
    const ull uhB = bperm64b(uh, bl << 2);
    const size_t ob = ((size_t)blockIdx.x * 2 + d) * 64;
    out[ob + w] = (float)((uhB >> w) & 1ULL);
    out[ob + 32 + w] = (float)((uhB >> (w + 32)) & 1ULL);
}

extern "C" void kernel_launch(void* const* d_in, const int* in_sizes, int n_in,
                              void* d_out, int out_size, void* d_ws, size_t ws_size,
                              hipStream_t stream) {
    (void)n_in; (void)out_size; (void)d_ws; (void)ws_size;
    const float* in = (const float*)d_in[0];
    float* out = (float*)d_out;
    const int batch = in_sizes[0] / 128;  // 2048
    scl_kernel<<<dim3(batch / 2), dim3(64), 0, stream>>>(in, out);
}

// Round 9
// 53.434 us; speedup vs baseline: 1.7324x; 1.1668x over previous
//
#include <hip/hip_runtime.h>
#include <math.h>

#define LMAX 30.0f
typedef unsigned long long ull;
typedef unsigned int u32;

__device__ __forceinline__ float clip30(float x) { return fminf(fmaxf(x, -LMAX), LMAX); }
__device__ __forceinline__ float cnop(float x, float y) {
    x = clip30(x); y = clip30(y);
    const float m = fminf(fabsf(x), fabsf(y));
    const unsigned sg = (__float_as_uint(x) ^ __float_as_uint(y)) & 0x80000000u;
    return __uint_as_float(__float_as_uint(m) | sg);
}

#define SWZI(x, PAT) __builtin_amdgcn_ds_swizzle((x), (PAT))
#define SWZF(x, PAT) __int_as_float(__builtin_amdgcn_ds_swizzle(__float_as_int(x), (PAT)))

template<int CTRL>
__device__ __forceinline__ int dppi(int x) {
    return __builtin_amdgcn_update_dpp(x, x, CTRL, 0xF, 0xF, false);
}
template<int CTRL>
__device__ __forceinline__ float dppf(float x) {
    return __int_as_float(dppi<CTRL>(__float_as_int(x)));
}
#define CTL_XOR8 0x128  /* row_ror:8 == xor-8 within 16-lane rows */
#define CTL_XOR2 0x4E   /* quad_perm [2,3,0,1] */
#define CTL_XOR1 0xB1   /* quad_perm [1,0,3,2] */

#if __has_builtin(__builtin_amdgcn_permlane16_swap)
typedef int v2j_ __attribute__((ext_vector_type(2)));
__device__ __forceinline__ int swap16i(int x) {
    v2j_ r = __builtin_amdgcn_permlane16_swap(x, x, false, false);
    return (r[0] != x) ? r[0] : r[1];
}
#else
__device__ __forceinline__ int swap16i(int x) { return SWZI(x, 0x401F); }
#endif
__device__ __forceinline__ float swap16f(float x) { return __int_as_float(swap16i(__float_as_int(x))); }

__device__ __forceinline__ float gfb(float v, int a) {
    return __int_as_float(__builtin_amdgcn_ds_bpermute(a, __float_as_int(v)));
}
__device__ __forceinline__ u32 gub(u32 v, int a) {
    return (u32)__builtin_amdgcn_ds_bpermute(a, (int)v);
}

// 32-bit funnel window of (hi:lo) starting at constexpr bit LO
template<int LO>
__device__ __forceinline__ u32 gbits(u32 lo, u32 hi) {
    if constexpr (LO >= 32) return hi >> (LO - 32);
    else if constexpr (LO == 0) return lo;
    else return (lo >> LO) | (hi << (32 - LO));
}

// polar encode folds
__device__ __forceinline__ u32 enc2(u32 w)  { w ^= (w >> 1) & 0x1u; return w; }
__device__ __forceinline__ u32 enc4(u32 w)  { w ^= (w >> 1) & 0x5u; w ^= (w >> 2) & 0x3u; return w; }
__device__ __forceinline__ u32 enc8(u32 w)  { w ^= (w >> 1) & 0x55u; w ^= (w >> 2) & 0x33u;
                                              w ^= (w >> 4) & 0x0fu; return w; }
__device__ __forceinline__ u32 enc16(u32 w) { w ^= (w >> 1) & 0x5555u; w ^= (w >> 2) & 0x3333u;
                                              w ^= (w >> 4) & 0x0f0fu; w ^= (w >> 8) & 0x00ffu; return w; }
__device__ __forceinline__ u32 enc32(u32 w) { w ^= (w >> 1) & 0x55555555u; w ^= (w >> 2) & 0x33333333u;
                                              w ^= (w >> 4) & 0x0f0f0f0fu; w ^= (w >> 8) & 0x00ff00ffu;
                                              w ^= (w >> 16) & 0x0000ffffu; return w; }

// ---- 2 decoders/wave; within decoder: pos = lane&15, row q = (lane>>4)&1.
// Distributed over rows (stride 2): C[32], S5[16], S4[8], S3[4].
// Replicated per row: R2[4], R1[2]. All state in registers.
struct Dec {
    float C[32];
    float S5[16], S4[8], S3[4], R2[4], R1[2];
    float pm;
    u32 uhLo, uhHi;
    int rF;
    int q, pos, gbase, A0, idx0;
    u32 upB;
    bool isUp;
};

__device__ __forceinline__ void f6(Dec& s) {
    #pragma unroll
    for (int k = 0; k < 16; ++k) s.S5[k] = cnop(s.C[k], s.C[k + 16]);
}
template<int II> __device__ __forceinline__ void g6(Dec& s) {
    const u32 ub = enc32(gbits<II - 96>(s.uhLo, s.uhHi));
    #pragma unroll
    for (int k = 0; k < 16; ++k) {
        const int u = (ub >> (s.q + 2 * k)) & 1;
        s.S5[k] = u ? (s.C[k + 16] - s.C[k]) : (s.C[k + 16] + s.C[k]);
    }
}
__device__ __forceinline__ void f5(Dec& s) {
    #pragma unroll
    for (int k = 0; k < 8; ++k) s.S4[k] = cnop(s.S5[k], s.S5[k + 8]);
}
template<int II> __device__ __forceinline__ void g5(Dec& s) {
    const u32 ub = enc16(gbits<II - 80>(s.uhLo, s.uhHi) & 0xffffu);
    #pragma unroll
    for (int k = 0; k < 8; ++k) {
        const int u = (ub >> (s.q + 2 * k)) & 1;
        s.S4[k] = u ? (s.S5[k + 8] - s.S5[k]) : (s.S5[k + 8] + s.S5[k]);
    }
}
__device__ __forceinline__ void f4(Dec& s) {
    #pragma unroll
    for (int k = 0; k < 4; ++k) s.S3[k] = cnop(s.S4[k], s.S4[k + 4]);
}
template<int II> __device__ __forceinline__ void g4(Dec& s) {
    const u32 ub = enc8(gbits<II - 72>(s.uhLo, s.uhHi) & 0xffu);
    #pragma unroll
    for (int k = 0; k < 4; ++k) {
        const int u = (ub >> (s.q + 2 * k)) & 1;
        s.S3[k] = u ? (s.S4[k + 4] - s.S4[k]) : (s.S4[k + 4] + s.S4[k]);
    }
}
__device__ __forceinline__ void repl2(Dec& s, float t0, float t1) {
    const float P0 = swap16f(t0), P1 = swap16f(t1);
    s.R2[0] = s.q ? P0 : t0; s.R2[1] = s.q ? t0 : P0;
    s.R2[2] = s.q ? P1 : t1; s.R2[3] = s.q ? t1 : P1;
}
__device__ __forceinline__ void f3r(Dec& s) {
    repl2(s, cnop(s.S3[0], s.S3[2]), cnop(s.S3[1], s.S3[3]));
}
template<int II> __device__ __forceinline__ void g3r(Dec& s) {
    const u32 ub = enc4(gbits<II - 68>(s.uhLo, s.uhHi) & 0xfu);
    const int u0 = (ub >> s.q) & 1, u1 = (ub >> (s.q + 2)) & 1;
    repl2(s, u0 ? (s.S3[2] - s.S3[0]) : (s.S3[2] + s.S3[0]),
             u1 ? (s.S3[3] - s.S3[1]) : (s.S3[3] + s.S3[1]));
}
__device__ __forceinline__ void f2(Dec& s) {
    s.R1[0] = cnop(s.R2[0], s.R2[2]); s.R1[1] = cnop(s.R2[1], s.R2[3]);
}
template<int II> __device__ __forceinline__ void g2(Dec& s) {
    const u32 ub = enc2(gbits<II - 66>(s.uhLo, s.uhHi) & 3u);
    s.R1[0] = (ub & 1) ? (s.R2[2] - s.R2[0]) : (s.R2[2] + s.R2[0]);
    s.R1[1] = (ub & 2) ? (s.R2[3] - s.R2[1]) : (s.R2[3] + s.R2[1]);
}

// leaf: decision + pm + distributed stable rank + invrank clone.
// Clone pruning: seg s cloned iff live (bit(s-1)(II)==0) AND path-dependent
// (II >= 64 + 2^s; uniform before — written only by the all-F descent at 64).
template<int II, bool CLONE>
__device__ __forceinline__ void leaf(Dec& s, float l0) {
    if constexpr (II - 64 < 32) s.uhLo |= s.upB << (II - 64);
    else                        s.uhHi |= s.upB << (II - 96);
    const float l = clip30(l0);
    const float tail = log1pf(expf(-fabsf(l)));
    s.pm += (s.isUp ? fmaxf(l, 0.0f) : fmaxf(-l, 0.0f)) + tail;
    int r = 0;
    {
        const u32 pmB = __float_as_uint(s.pm);
        #pragma unroll
        for (int k = 0; k < 8; ++k) {
            const u32 pmj = gub((u32)__float_as_int(s.pm) * 0u + (u32)0, 0) * 0u; // placeholder elided
        }
    }
    (void)r;
}

// NOTE: placeholder above removed — real implementation below.
template<int II, bool CLONE>
__device__ __forceinline__ void leafR(Dec& s, float l0) {
    if constexpr (II - 64 < 32) s.uhLo |= s.upB << (II - 64);
    else                        s.uhHi |= s.upB << (II - 96);
    const float l = clip30(l0);
    const float tail = log1pf(expf(-fabsf(l)));
    s.pm += (s.isUp ? fmaxf(l, 0.0f) : fmaxf(-l, 0.0f)) + tail;
    int r = 0;
    {
        const u32 pmB = __float_as_uint(s.pm);
        #pragma unroll
        for (int k = 0; k < 8; ++k) {
            const u32 pmj = (u32)__builtin_amdgcn_ds_bpermute(s.A0 + 4 * k, __float_as_int(s.pm));
            r += ((pmj < pmB) || (pmj == pmB && (s.idx0 + k) < s.pos)) ? 1 : 0;
        }
    }
    r += swap16i(r);
    s.rF = r;
    if constexpr (CLONE) {
        const int inv = __builtin_amdgcn_ds_permute((r | s.gbase) << 2, s.pos);
        const int p8 = dppi<CTL_XOR8>(inv);
        const int ga = ((s.isUp ? p8 : inv) | s.gbase) << 2;
        s.pm = gfb(s.pm, ga);
        s.uhLo = gub(s.uhLo, ga);
        if constexpr (II >= 96) s.uhHi = gub(s.uhHi, ga);
        if constexpr ((((II) >> 0) & 1) == 0 && II >= 66) {
            s.R1[0] = gfb(s.R1[0], ga); s.R1[1] = gfb(s.R1[1], ga);
        }
        if constexpr ((((II) >> 1) & 1) == 0 && II >= 68) {
            #pragma unroll
            for (int e = 0; e < 4; ++e) s.R2[e] = gfb(s.R2[e], ga);
        }
        if constexpr ((((II) >> 2) & 1) == 0 && II >= 72) {
            #pragma unroll
            for (int e = 0; e < 4; ++e) s.S3[e] = gfb(s.S3[e], ga);
        }
        if constexpr ((((II) >> 3) & 1) == 0 && II >= 80) {
            #pragma unroll
            for (int e = 0; e < 8; ++e) s.S4[e] = gfb(s.S4[e], ga);
        }
        if constexpr ((((II) >> 4) & 1) == 0 && II >= 96) {
            #pragma unroll
            for (int e = 0; e < 16; ++e) s.S5[e] = gfb(s.S5[e], ga);
        }
    }
}

template<int II> __device__ __forceinline__ void evenLeaf(Dec& s) {
    constexpr int t = (II == 64) ? 6 : __builtin_ctz(II);
    if constexpr (t >= 6) f6(s);
    if constexpr (t == 5) g6<II>(s);
    if constexpr (t >= 5) f5(s);
    if constexpr (t == 4) g5<II>(s);
    if constexpr (t >= 4) f4(s);
    if constexpr (t == 3) g4<II>(s);
    if constexpr (t >= 3) f3r(s);
    if constexpr (t == 2) g3r<II>(s);
    if constexpr (t >= 2) f2(s);
    if constexpr (t == 1) g2<II>(s);
    const float l0 = cnop(s.R1[0], s.R1[1]);
    leafR<II, true>(s, l0);
}
template<int II> __device__ __forceinline__ void oddLeaf(Dec& s) {
    const int ug = (int)(gbits<II - 65>(s.uhLo, s.uhHi) & 1u);
    const float l0 = ug ? (s.R1[1] - s.R1[0]) : (s.R1[1] + s.R1[0]);
    leafR<II, (II != 127)>(s, l0);
}
template<int II> __device__ __forceinline__ void runPairs(Dec& s) {
    evenLeaf<II>(s);
    oddLeaf<II + 1>(s);
    if constexpr (II + 2 < 128) runPairs<II + 2>(s);
}

#define RLF(x, J) __uint_as_float((u32)__builtin_amdgcn_readlane(__float_as_int(x), (J)))

__global__ __launch_bounds__(64) void scl_kernel(const float* __restrict__ in,
                                                 float* __restrict__ out) {
    __shared__ float chS[128];
    const int lane = threadIdx.x;
    const int w = lane & 31;
    const int d = lane >> 5;
    const int dbase = lane & 32;

    Dec s;
    s.pos = lane & 15;
    s.q = (lane >> 4) & 1;
    s.gbase = lane & 48;
    s.isUp = (lane & 8) != 0;
    s.upB = (u32)((lane >> 3) & 1);
    s.idx0 = s.q << 3;
    s.A0 = (dbase | (s.q << 3)) << 2;
    s.uhLo = 0; s.uhHi = 0; s.rF = 0;

    const size_t base = ((size_t)blockIdx.x * 2 + d) * 128;
    const float a1 = -in[base + w],      c1 = -in[base + 64 + w];
    const float a2 = -in[base + 32 + w], c2 = -in[base + 96 + w];
    chS[d * 64 + w] = a1 + c1;            // stage-6 right-subtree llr (u=0 g)
    chS[d * 64 + 32 + w] = a2 + c2;
    __syncthreads();
    #pragma unroll
    for (int k = 0; k < 32; ++k) s.C[k] = chS[d * 64 + s.q + 2 * k];

    // ---- frozen half: all paths identical, u == 0; butterfly
    float v1 = cnop(a1, c1), v2 = cnop(a2, c2);
    { const float n1 = cnop(v1, v2); v2 = v1 + v2; v1 = n1; }             // h=32
    { const float o1 = swap16f(v1), o2 = swap16f(v2);                      // h=16
      v1 = (w & 16) ? (o1 + v1) : cnop(v1, o1);
      v2 = (w & 16) ? (o2 + v2) : cnop(v2, o2); }
    { const float o1 = dppf<CTL_XOR8>(v1), o2 = dppf<CTL_XOR8>(v2);        // h=8
      v1 = (w & 8) ? (o1 + v1) : cnop(v1, o1);
      v2 = (w & 8) ? (o2 + v2) : cnop(v2, o2); }
    { const float o1 = SWZF(v1, 0x101F), o2 = SWZF(v2, 0x101F);            // h=4
      v1 = (w & 4) ? (o1 + v1) : cnop(v1, o1);
      v2 = (w & 4) ? (o2 + v2) : cnop(v2, o2); }
    { const float o1 = dppf<CTL_XOR2>(v1), o2 = dppf<CTL_XOR2>(v2);        // h=2
      v1 = (w & 2) ? (o1 + v1) : cnop(v1, o1);
      v2 = (w & 2) ? (o2 + v2) : cnop(v2, o2); }
    { const float o1 = dppf<CTL_XOR1>(v1), o2 = dppf<CTL_XOR1>(v2);        // h=1
      v1 = (w & 1) ? (o1 + v1) : cnop(v1, o1);
      v2 = (w & 1) ? (o2 + v2) : cnop(v2, o2); }
    const float sp1 = fmaxf(-clip30(v1), 0.0f) + log1pf(expf(-fabsf(clip30(v1))));
    const float sp2 = fmaxf(-clip30(v2), 0.0f) + log1pf(expf(-fabsf(clip30(v2))));

    // exact sequential pm accumulation per decoder (reference FP order)
    s.pm = ((s.pos == 0) || (s.pos == 8)) ? 0.0f : LMAX;
    if (lane < 32) {
        #pragma unroll
        for (int j = 0; j < 32; ++j) s.pm += RLF(sp1, j);
        #pragma unroll
        for (int j = 0; j < 32; ++j) s.pm += RLF(sp2, j);
    } else {
        #pragma unroll
        for (int j = 32; j < 64; ++j) s.pm += RLF(sp1, j);
        #pragma unroll
        for (int j = 32; j < 64; ++j) s.pm += RLF(sp2, j);
    }

    // ---- info half, fully unrolled (static II) ----
    runPairs<64>(s);

    // best path per decoder = rank 0
    const ull m = __ballot(s.rF == 0);
    const int bl = dbase + (int)__builtin_ctz((u32)(m >> dbase));
    const u32 lo = gub(s.uhLo, bl << 2);
    const u32 hi = gub(s.uhHi, bl << 2);
    const ull uhB = ((ull)hi << 32) | lo;
    const size_t ob = ((size_t)blockIdx.x * 2 + d) * 64;
    out[ob + w] = (float)((uhB >> w) & 1ULL);
    out[ob + 32 + w] = (float)((uhB >> (w + 32)) & 1ULL);
}

extern "C" void kernel_launch(void* const* d_in, const int* in_sizes, int n_in,
                              void* d_out, int out_size, void* d_ws, size_t ws_size,
                              hipStream_t stream) {
    (void)n_in; (void)out_size; (void)d_ws; (void)ws_size;
    const float* in = (const float*)d_in[0];
    float* out = (float*)d_out;
    const int batch = in_sizes[0] / 128;  // 2048
    scl_kernel<<<dim3(batch / 2), dim3(64), 0, stream>>>(in, out);
}

// Round 10
// 52.903 us; speedup vs baseline: 1.7498x; 1.0100x over previous
//
#include <hip/hip_runtime.h>
#include <math.h>

#define LMAX 30.0f
typedef unsigned long long ull;
typedef unsigned int u32;

__device__ __forceinline__ float clip30(float x) { return fminf(fmaxf(x, -LMAX), LMAX); }
__device__ __forceinline__ float cnop(float x, float y) {
    x = clip30(x); y = clip30(y);
    const float m = fminf(fabsf(x), fabsf(y));
    const unsigned sg = (__float_as_uint(x) ^ __float_as_uint(y)) & 0x80000000u;
    return __uint_as_float(__float_as_uint(m) | sg);
}

#define SWZI(x, PAT) __builtin_amdgcn_ds_swizzle((x), (PAT))
#define SWZF(x, PAT) __int_as_float(__builtin_amdgcn_ds_swizzle(__float_as_int(x), (PAT)))

template<int CTRL>
__device__ __forceinline__ int dppi(int x) {
    return __builtin_amdgcn_update_dpp(x, x, CTRL, 0xF, 0xF, false);
}
template<int CTRL>
__device__ __forceinline__ float dppf(float x) {
    return __int_as_float(dppi<CTRL>(__float_as_int(x)));
}
#define CTL_XOR8 0x128  /* row_ror:8 == xor-8 within 16-lane rows */
#define CTL_XOR2 0x4E   /* quad_perm [2,3,0,1] */
#define CTL_XOR1 0xB1   /* quad_perm [1,0,3,2] */

#if __has_builtin(__builtin_amdgcn_permlane16_swap)
typedef int v2j_ __attribute__((ext_vector_type(2)));
__device__ __forceinline__ int swap16i(int x) {
    v2j_ r = __builtin_amdgcn_permlane16_swap(x, x, false, false);
    return (r[0] != x) ? r[0] : r[1];
}
#else
__device__ __forceinline__ int swap16i(int x) { return SWZI(x, 0x401F); }
#endif
__device__ __forceinline__ float swap16f(float x) { return __int_as_float(swap16i(__float_as_int(x))); }

__device__ __forceinline__ float gfb(float v, int a) {
    return __int_as_float(__builtin_amdgcn_ds_bpermute(a, __float_as_int(v)));
}
__device__ __forceinline__ u32 gub(u32 v, int a) {
    return (u32)__builtin_amdgcn_ds_bpermute(a, (int)v);
}

// polar encode folds
__device__ __forceinline__ u32 enc2(u32 w)  { w ^= (w >> 1) & 0x1u; return w; }
__device__ __forceinline__ u32 enc4(u32 w)  { w ^= (w >> 1) & 0x5u; w ^= (w >> 2) & 0x3u; return w; }
__device__ __forceinline__ u32 enc8(u32 w)  { w ^= (w >> 1) & 0x55u; w ^= (w >> 2) & 0x33u;
                                              w ^= (w >> 4) & 0x0fu; return w; }
__device__ __forceinline__ u32 enc16(u32 w) { w ^= (w >> 1) & 0x5555u; w ^= (w >> 2) & 0x3333u;
                                              w ^= (w >> 4) & 0x0f0fu; w ^= (w >> 8) & 0x00ffu; return w; }
__device__ __forceinline__ u32 enc32(u32 w) { w ^= (w >> 1) & 0x55555555u; w ^= (w >> 2) & 0x33333333u;
                                              w ^= (w >> 4) & 0x0f0f0f0fu; w ^= (w >> 8) & 0x00ff00ffu;
                                              w ^= (w >> 16) & 0x0000ffffu; return w; }

// ---- 2 decoders/wave; within decoder: pos = lane&15, row q = (lane>>4)&1.
// Distributed over rows (stride 2): C[32], S5[16], S4[8], S3[4].
// Replicated per row: R2[4], R1[2]. uhat: 32-bit word per 32-leaf half
// (uhCur = current half, uhPrev = previous half). All state in registers.
struct Dec {
    float C[32];
    float S5[16], S4[8], S3[4], R2[4], R1[2];
    float pm;
    u32 uhPrev, uhCur;
    int rF;
    int q, pos, gbase, A0, idx0;
    u32 upB;
    bool isUp;
};

__device__ __forceinline__ void f6(Dec& s) {
    #pragma unroll
    for (int k = 0; k < 16; ++k) s.S5[k] = cnop(s.C[k], s.C[k + 16]);
}
// head of half 1: g at stage 6, u bits = encode of previous half's uhat word
__device__ __forceinline__ void g6p(Dec& s) {
    const u32 ub = enc32(s.uhPrev);
    #pragma unroll
    for (int k = 0; k < 16; ++k) {
        const int u = (ub >> (s.q + 2 * k)) & 1;
        s.S5[k] = u ? (s.C[k + 16] - s.C[k]) : (s.C[k + 16] + s.C[k]);
    }
}
__device__ __forceinline__ void f5(Dec& s) {
    #pragma unroll
    for (int k = 0; k < 8; ++k) s.S4[k] = cnop(s.S5[k], s.S5[k + 8]);
}
template<int L> __device__ __forceinline__ void g5l(Dec& s) {  // L == 16
    const u32 ub = enc16((s.uhCur >> (L - 16)) & 0xffffu);
    #pragma unroll
    for (int k = 0; k < 8; ++k) {
        const int u = (ub >> (s.q + 2 * k)) & 1;
        s.S4[k] = u ? (s.S5[k + 8] - s.S5[k]) : (s.S5[k + 8] + s.S5[k]);
    }
}
__device__ __forceinline__ void f4(Dec& s) {
    #pragma unroll
    for (int k = 0; k < 4; ++k) s.S3[k] = cnop(s.S4[k], s.S4[k + 4]);
}
template<int L> __device__ __forceinline__ void g4l(Dec& s) {
    const u32 ub = enc8((s.uhCur >> (L - 8)) & 0xffu);
    #pragma unroll
    for (int k = 0; k < 4; ++k) {
        const int u = (ub >> (s.q + 2 * k)) & 1;
        s.S3[k] = u ? (s.S4[k + 4] - s.S4[k]) : (s.S4[k + 4] + s.S4[k]);
    }
}
__device__ __forceinline__ void repl2(Dec& s, float t0, float t1) {
    const float P0 = swap16f(t0), P1 = swap16f(t1);
    s.R2[0] = s.q ? P0 : t0; s.R2[1] = s.q ? t0 : P0;
    s.R2[2] = s.q ? P1 : t1; s.R2[3] = s.q ? t1 : P1;
}
__device__ __forceinline__ void f3r(Dec& s) {
    repl2(s, cnop(s.S3[0], s.S3[2]), cnop(s.S3[1], s.S3[3]));
}
template<int L> __device__ __forceinline__ void g3rl(Dec& s) {
    const u32 ub = enc4((s.uhCur >> (L - 4)) & 0xfu);
    const int u0 = (ub >> s.q) & 1, u1 = (ub >> (s.q + 2)) & 1;
    repl2(s, u0 ? (s.S3[2] - s.S3[0]) : (s.S3[2] + s.S3[0]),
             u1 ? (s.S3[3] - s.S3[1]) : (s.S3[3] + s.S3[1]));
}
__device__ __forceinline__ void f2(Dec& s) {
    s.R1[0] = cnop(s.R2[0], s.R2[2]); s.R1[1] = cnop(s.R2[1], s.R2[3]);
}
template<int L> __device__ __forceinline__ void g2l(Dec& s) {
    const u32 ub = enc2((s.uhCur >> (L - 2)) & 3u);
    s.R1[0] = (ub & 1) ? (s.R2[2] - s.R2[0]) : (s.R2[2] + s.R2[0]);
    s.R1[1] = (ub & 2) ? (s.R2[3] - s.R2[1]) : (s.R2[3] + s.R2[1]);
}

// leaf: decision + pm + distributed stable rank + invrank clone.
// CLONEMODE: 0 = never, 1 = always, 2 = only when h == 0 (leaf L=31).
// Liveness from local leaf index L (bits of global II == bits of L, L < 32).
template<int L, int CLONEMODE>
__device__ __forceinline__ void leafR(Dec& s, float l0, int h) {
    s.uhCur |= s.upB << L;
    const float l = clip30(l0);
    const float tail = log1pf(expf(-fabsf(l)));
    s.pm += (s.isUp ? fmaxf(l, 0.0f) : fmaxf(-l, 0.0f)) + tail;
    int r = 0;
    {
        const u32 pmB = __float_as_uint(s.pm);
        #pragma unroll
        for (int k = 0; k < 8; ++k) {
            const u32 pmj = (u32)__builtin_amdgcn_ds_bpermute(s.A0 + 4 * k, __float_as_int(s.pm));
            r += ((pmj < pmB) || (pmj == pmB && (s.idx0 + k) < s.pos)) ? 1 : 0;
        }
    }
    r += swap16i(r);
    s.rF = r;
    if constexpr (CLONEMODE != 0) {
        if (CLONEMODE == 1 || h == 0) {
            const int inv = __builtin_amdgcn_ds_permute((r | s.gbase) << 2, s.pos);
            const int p8 = dppi<CTL_XOR8>(inv);
            const int ga = ((s.isUp ? p8 : inv) | s.gbase) << 2;
            s.pm = gfb(s.pm, ga);
            s.uhCur = gub(s.uhCur, ga);
            if (h != 0) s.uhPrev = gub(s.uhPrev, ga);
            if constexpr ((L & 1) == 0) {
                s.R1[0] = gfb(s.R1[0], ga); s.R1[1] = gfb(s.R1[1], ga);
            }
            if constexpr ((L & 2) == 0) {
                #pragma unroll
                for (int e = 0; e < 4; ++e) s.R2[e] = gfb(s.R2[e], ga);
            }
            if constexpr ((L & 4) == 0) {
                #pragma unroll
                for (int e = 0; e < 4; ++e) s.S3[e] = gfb(s.S3[e], ga);
            }
            if constexpr ((L & 8) == 0) {
                #pragma unroll
                for (int e = 0; e < 8; ++e) s.S4[e] = gfb(s.S4[e], ga);
            }
            if constexpr ((L & 16) == 0) {
                #pragma unroll
                for (int e = 0; e < 16; ++e) s.S5[e] = gfb(s.S5[e], ga);
            }
        }
    }
}

template<int J> __device__ __forceinline__ void evenL(Dec& s, int h) {
    constexpr int t = __builtin_ctz(J);   // J even, 2..30 -> t in 1..4
    if constexpr (t == 4) g5l<J>(s);
    if constexpr (t >= 4) f4(s);
    if constexpr (t == 3) g4l<J>(s);
    if constexpr (t >= 3) f3r(s);
    if constexpr (t == 2) g3rl<J>(s);
    if constexpr (t >= 2) f2(s);
    if constexpr (t == 1) g2l<J>(s);
    const float l0 = cnop(s.R1[0], s.R1[1]);
    leafR<J, 1>(s, l0, h);
}
template<int J> __device__ __forceinline__ void oddL(Dec& s, int h) {
    const int ug = (int)((s.uhCur >> (J - 1)) & 1u);
    const float l0 = ug ? (s.R1[1] - s.R1[0]) : (s.R1[1] + s.R1[0]);
    leafR<J, (J == 31 ? 2 : 1)>(s, l0, h);
}
template<int J> __device__ __forceinline__ void pairs(Dec& s, int h) {
    evenL<J>(s, h);
    oddL<J + 1>(s, h);
    if constexpr (J + 2 <= 30) pairs<J + 2>(s, h);
}

#define RLF(x, J) __uint_as_float((u32)__builtin_amdgcn_readlane(__float_as_int(x), (J)))

__global__ __launch_bounds__(64) void scl_kernel(const float* __restrict__ in,
                                                 float* __restrict__ out) {
    __shared__ float chS[128];
    const int lane = threadIdx.x;
    const int w = lane & 31;
    const int d = lane >> 5;
    const int dbase = lane & 32;

    Dec s;
    s.pos = lane & 15;
    s.q = (lane >> 4) & 1;
    s.gbase = lane & 48;
    s.isUp = (lane & 8) != 0;
    s.upB = (u32)((lane >> 3) & 1);
    s.idx0 = s.q << 3;
    s.A0 = (dbase | (s.q << 3)) << 2;
    s.uhPrev = 0; s.uhCur = 0; s.rF = 0;

    const size_t base = ((size_t)blockIdx.x * 2 + d) * 128;
    const float a1 = -in[base + w],      c1 = -in[base + 64 + w];
    const float a2 = -in[base + 32 + w], c2 = -in[base + 96 + w];
    chS[d * 64 + w] = a1 + c1;            // stage-6 right-subtree llr (u=0 g)
    chS[d * 64 + 32 + w] = a2 + c2;
    __syncthreads();
    #pragma unroll
    for (int k = 0; k < 32; ++k) s.C[k] = chS[d * 64 + s.q + 2 * k];

    // ---- frozen half (leaves 0..63): all paths identical, u == 0; butterfly
    float v1 = cnop(a1, c1), v2 = cnop(a2, c2);
    { const float n1 = cnop(v1, v2); v2 = v1 + v2; v1 = n1; }             // h=32
    { const float o1 = swap16f(v1), o2 = swap16f(v2);                      // h=16
      v1 = (w & 16) ? (o1 + v1) : cnop(v1, o1);
      v2 = (w & 16) ? (o2 + v2) : cnop(v2, o2); }
    { const float o1 = dppf<CTL_XOR8>(v1), o2 = dppf<CTL_XOR8>(v2);        // h=8
      v1 = (w & 8) ? (o1 + v1) : cnop(v1, o1);
      v2 = (w & 8) ? (o2 + v2) : cnop(v2, o2); }
    { const float o1 = SWZF(v1, 0x101F), o2 = SWZF(v2, 0x101F);            // h=4
      v1 = (w & 4) ? (o1 + v1) : cnop(v1, o1);
      v2 = (w & 4) ? (o2 + v2) : cnop(v2, o2); }
    { const float o1 = dppf<CTL_XOR2>(v1), o2 = dppf<CTL_XOR2>(v2);        // h=2
      v1 = (w & 2) ? (o1 + v1) : cnop(v1, o1);
      v2 = (w & 2) ? (o2 + v2) : cnop(v2, o2); }
    { const float o1 = dppf<CTL_XOR1>(v1), o2 = dppf<CTL_XOR1>(v2);        // h=1
      v1 = (w & 1) ? (o1 + v1) : cnop(v1, o1);
      v2 = (w & 1) ? (o2 + v2) : cnop(v2, o2); }
    const float sp1 = fmaxf(-clip30(v1), 0.0f) + log1pf(expf(-fabsf(clip30(v1))));
    const float sp2 = fmaxf(-clip30(v2), 0.0f) + log1pf(expf(-fabsf(clip30(v2))));

    // exact sequential pm accumulation per decoder (reference FP order)
    s.pm = ((s.pos == 0) || (s.pos == 8)) ? 0.0f : LMAX;
    if (lane < 32) {
        #pragma unroll
        for (int j = 0; j < 32; ++j) s.pm += RLF(sp1, j);
        #pragma unroll
        for (int j = 0; j < 32; ++j) s.pm += RLF(sp2, j);
    } else {
        #pragma unroll
        for (int j = 32; j < 64; ++j) s.pm += RLF(sp1, j);
        #pragma unroll
        for (int j = 32; j < 64; ++j) s.pm += RLF(sp2, j);
    }

    // ---- info half: two 32-leaf halves sharing one unrolled body ----
    #pragma unroll 1
    for (int h = 0; h < 2; ++h) {
        if (h == 0) f6(s); else g6p(s);    // half head: leaf 64 / leaf 96
        f5(s); f4(s); f3r(s); f2(s);
        { const float l0 = cnop(s.R1[0], s.R1[1]); leafR<0, 1>(s, l0, h); }
        oddL<1>(s, h);
        pairs<2>(s, h);
        if (h == 0) { s.uhPrev = s.uhCur; s.uhCur = 0; }
    }

    // best path per decoder = rank 0
    const ull m = __ballot(s.rF == 0);
    const int bl = dbase + (int)__builtin_ctz((u32)(m >> dbase));
    const u32 b0 = gub(s.uhPrev, bl << 2);   // info bits 0..31  (leaves 64..95)
    const u32 b1 = gub(s.uhCur, bl << 2);    // info bits 32..63 (leaves 96..127)
    const size_t ob = ((size_t)blockIdx.x * 2 + d) * 64;
    out[ob + w] = (float)((b0 >> w) & 1u);
    out[ob + 32 + w] = (float)((b1 >> w) & 1u);
}

extern "C" void kernel_launch(void* const* d_in, const int* in_sizes, int n_in,
                              void* d_out, int out_size, void* d_ws, size_t ws_size,
                              hipStream_t stream) {
    (void)n_in; (void)out_size; (void)d_ws; (void)ws_size;
    const float* in = (const float*)d_in[0];
    float* out = (float*)d_out;
    const int batch = in_sizes[0] / 128;  // 2048
    scl_kernel<<<dim3(batch / 2), dim3(64), 0, stream>>>(in, out);
}

// Round 11
// 51.888 us; speedup vs baseline: 1.7840x; 1.0196x over previous
//
#include <hip/hip_runtime.h>
#include <math.h>

#define LMAX 30.0f
typedef unsigned long long ull;
typedef unsigned int u32;

__device__ __forceinline__ float clip30(float x) { return fminf(fmaxf(x, -LMAX), LMAX); }
__device__ __forceinline__ float cnop(float x, float y) {
    x = clip30(x); y = clip30(y);
    const float m = fminf(fabsf(x), fabsf(y));
    const unsigned sg = (__float_as_uint(x) ^ __float_as_uint(y)) & 0x80000000u;
    return __uint_as_float(__float_as_uint(m) | sg);
}

#define SWZF(x, PAT) __int_as_float(__builtin_amdgcn_ds_swizzle(__float_as_int(x), (PAT)))

template<int CTRL>
__device__ __forceinline__ int dppi(int x) {
    return __builtin_amdgcn_update_dpp(x, x, CTRL, 0xF, 0xF, false);
}
template<int CTRL>
__device__ __forceinline__ float dppf(float x) {
    return __int_as_float(dppi<CTRL>(__float_as_int(x)));
}
#define CTL_XOR8 0x128  /* row_ror:8 == xor-8 within 16-lane rows */
#define CTL_XOR2 0x4E   /* quad_perm [2,3,0,1] */
#define CTL_XOR1 0xB1   /* quad_perm [1,0,3,2] */

#if __has_builtin(__builtin_amdgcn_permlane16_swap)
typedef int v2j_ __attribute__((ext_vector_type(2)));
__device__ __forceinline__ int swap16i(int x) {
    v2j_ r = __builtin_amdgcn_permlane16_swap(x, x, false, false);
    return (r[0] != x) ? r[0] : r[1];
}
#else
__device__ __forceinline__ int swap16i(int x) { return __builtin_amdgcn_ds_swizzle(x, 0x401F); }
#endif
__device__ __forceinline__ float swap16f(float x) { return __int_as_float(swap16i(__float_as_int(x))); }

__device__ __forceinline__ float gfb(float v, int a) {
    return __int_as_float(__builtin_amdgcn_ds_bpermute(a, __float_as_int(v)));
}
__device__ __forceinline__ u32 gub(u32 v, int a) {
    return (u32)__builtin_amdgcn_ds_bpermute(a, (int)v);
}

// polar encode folds
__device__ __forceinline__ u32 enc2(u32 w)  { w ^= (w >> 1) & 0x1u; return w; }
__device__ __forceinline__ u32 enc4(u32 w)  { w ^= (w >> 1) & 0x5u; w ^= (w >> 2) & 0x3u; return w; }
__device__ __forceinline__ u32 enc8(u32 w)  { w ^= (w >> 1) & 0x55u; w ^= (w >> 2) & 0x33u;
                                              w ^= (w >> 4) & 0x0fu; return w; }
__device__ __forceinline__ u32 enc16(u32 w) { w ^= (w >> 1) & 0x5555u; w ^= (w >> 2) & 0x3333u;
                                              w ^= (w >> 4) & 0x0f0fu; w ^= (w >> 8) & 0x00ffu; return w; }
__device__ __forceinline__ u32 enc32(u32 w) { w ^= (w >> 1) & 0x55555555u; w ^= (w >> 2) & 0x33333333u;
                                              w ^= (w >> 4) & 0x0f0f0f0fu; w ^= (w >> 8) & 0x00ff00ffu;
                                              w ^= (w >> 16) & 0x0000ffffu; return w; }

// ---- 2 decoders/wave; pos = lane&15, row q = (lane>>4)&1.
// Distributed over rows (stride 2): C[32], S5[16], S4[8], S3[4].
// Replicated per row: R2[4], R1[2]. uhat: u32 per 32-leaf half.
// S3/S4/S5 use DEFERRED cloning: per-segment source-map registers
// (mS3/mS4/mS5, 1 word) are cloned instead of the data; the data permutation
// is applied lazily at the segment's single cross-leaf read.
struct Dec {
    float C[32];
    float S5[16], S4[8], S3[4], R2[4], R1[2];
    float pm;
    u32 uhPrev, uhCur;
    int rF;
    int mS5, mS4, mS3;    // deferred-clone maps (pos 0..15)
    int q, pos, gbase, A0, idx0;
    u32 upB;
    bool isUp;
};

__device__ __forceinline__ void f6(Dec& s) {
    #pragma unroll
    for (int k = 0; k < 16; ++k) s.S5[k] = cnop(s.C[k], s.C[k + 16]);
}
__device__ __forceinline__ void g6p(Dec& s) {   // head of half 1
    const u32 ub = enc32(s.uhPrev);
    #pragma unroll
    for (int k = 0; k < 16; ++k) {
        const int u = (ub >> (s.q + 2 * k)) & 1;
        s.S5[k] = u ? (s.C[k + 16] - s.C[k]) : (s.C[k + 16] + s.C[k]);
    }
}
__device__ __forceinline__ void f5(Dec& s) {
    #pragma unroll
    for (int k = 0; k < 8; ++k) s.S4[k] = cnop(s.S5[k], s.S5[k + 8]);
}
// L == 16 only: deferred S5 read through mS5; writes S4 fresh -> reset mS4
__device__ __forceinline__ void g5l16(Dec& s) {
    const u32 ub = enc16(s.uhCur & 0xffffu);
    const int am = (s.mS5 | s.gbase) << 2;
    #pragma unroll
    for (int k = 0; k < 8; ++k) {
        const float x = gfb(s.S5[k], am), y = gfb(s.S5[k + 8], am);
        const int u = (ub >> (s.q + 2 * k)) & 1;
        s.S4[k] = u ? (y - x) : (y + x);
    }
    s.mS4 = s.pos;
}
__device__ __forceinline__ void f4(Dec& s) {
    #pragma unroll
    for (int k = 0; k < 4; ++k) s.S3[k] = cnop(s.S4[k], s.S4[k + 4]);
}
// L in {8,24}: deferred S4 read through mS4; writes S3 fresh -> reset mS3
template<int L> __device__ __forceinline__ void g4l(Dec& s) {
    const u32 ub = enc8((s.uhCur >> (L - 8)) & 0xffu);
    const int am = (s.mS4 | s.gbase) << 2;
    #pragma unroll
    for (int k = 0; k < 4; ++k) {
        const float x = gfb(s.S4[k], am), y = gfb(s.S4[k + 4], am);
        const int u = (ub >> (s.q + 2 * k)) & 1;
        s.S3[k] = u ? (y - x) : (y + x);
    }
    s.mS3 = s.pos;
}
__device__ __forceinline__ void repl2(Dec& s, float t0, float t1) {
    const float P0 = swap16f(t0), P1 = swap16f(t1);
    s.R2[0] = s.q ? P0 : t0; s.R2[1] = s.q ? t0 : P0;
    s.R2[2] = s.q ? P1 : t1; s.R2[3] = s.q ? t1 : P1;
}
__device__ __forceinline__ void f3r(Dec& s) {
    repl2(s, cnop(s.S3[0], s.S3[2]), cnop(s.S3[1], s.S3[3]));
}
// L in {4,12,20,28}: deferred S3 read through mS3
template<int L> __device__ __forceinline__ void g3rl(Dec& s) {
    const u32 ub = enc4((s.uhCur >> (L - 4)) & 0xfu);
    const int am = (s.mS3 | s.gbase) << 2;
    const float x0 = gfb(s.S3[0], am), x1 = gfb(s.S3[1], am);
    const float x2 = gfb(s.S3[2], am), x3 = gfb(s.S3[3], am);
    const int u0 = (ub >> s.q) & 1, u1 = (ub >> (s.q + 2)) & 1;
    repl2(s, u0 ? (x2 - x0) : (x2 + x0), u1 ? (x3 - x1) : (x3 + x1));
}
__device__ __forceinline__ void f2(Dec& s) {
    s.R1[0] = cnop(s.R2[0], s.R2[2]); s.R1[1] = cnop(s.R2[1], s.R2[3]);
}
template<int L> __device__ __forceinline__ void g2l(Dec& s) {
    const u32 ub = enc2((s.uhCur >> (L - 2)) & 3u);
    s.R1[0] = (ub & 1) ? (s.R2[2] - s.R2[0]) : (s.R2[2] + s.R2[0]);
    s.R1[1] = (ub & 2) ? (s.R2[3] - s.R2[1]) : (s.R2[3] + s.R2[1]);
}

// leaf: decision + pm + distributed stable rank + ballot-derived clone source
// (no ds_permute) + direct clone of pm/uh/R1/R2 + map-clone of S3/S4/S5.
template<int L, int CLONEMODE>   // 0 never, 1 always, 2 only h==0
__device__ __forceinline__ void leafR(Dec& s, float l0, int h) {
    s.uhCur |= s.upB << L;
    const float l = clip30(l0);
    const float tail = log1pf(expf(-fabsf(l)));
    s.pm += (s.isUp ? fmaxf(l, 0.0f) : fmaxf(-l, 0.0f)) + tail;
    int r = 0;
    {
        const u32 pmB = __float_as_uint(s.pm);
        #pragma unroll
        for (int k = 0; k < 8; ++k) {
            const u32 pmj = (u32)__builtin_amdgcn_ds_bpermute(s.A0 + 4 * k, __float_as_int(s.pm));
            r += ((pmj < pmB) || (pmj == pmB && (s.idx0 + k) < s.pos)) ? 1 : 0;
        }
    }
    r += swap16i(r);
    s.rF = r;
    if constexpr (CLONEMODE != 0) {
        if (CLONEMODE == 1 || h == 0) {
            // src = position holding rank (pos&7): 8 uniform ballots + select
            const ull b0 = __ballot(r == 0), b1 = __ballot(r == 1);
            const ull b2 = __ballot(r == 2), b3 = __ballot(r == 3);
            const ull b4 = __ballot(r == 4), b5 = __ballot(r == 5);
            const ull b6 = __ballot(r == 6), b7 = __ballot(r == 7);
            const ull t0 = (s.pos & 1) ? b1 : b0;
            const ull t1 = (s.pos & 1) ? b3 : b2;
            const ull t2 = (s.pos & 1) ? b5 : b4;
            const ull t3 = (s.pos & 1) ? b7 : b6;
            const ull u0 = (s.pos & 2) ? t1 : t0;
            const ull u1 = (s.pos & 2) ? t3 : t2;
            const ull bb = (s.pos & 4) ? u1 : u0;
            const u32 win = (u32)(bb >> s.gbase) & 0xFFFFu;
            const int ga = (((int)__builtin_ctz(win)) | s.gbase) << 2;
            s.pm = gfb(s.pm, ga);
            s.uhCur = gub(s.uhCur, ga);
            if (h != 0) s.uhPrev = gub(s.uhPrev, ga);
            if constexpr ((L & 1) == 0) {
                s.R1[0] = gfb(s.R1[0], ga); s.R1[1] = gfb(s.R1[1], ga);
            }
            if constexpr ((L & 2) == 0) {
                #pragma unroll
                for (int e = 0; e < 4; ++e) s.R2[e] = gfb(s.R2[e], ga);
            }
            if constexpr ((L & 4) == 0) s.mS3 = __builtin_amdgcn_ds_bpermute(ga, s.mS3);
            if constexpr ((L & 8) == 0) s.mS4 = __builtin_amdgcn_ds_bpermute(ga, s.mS4);
            if constexpr ((L & 16) == 0) s.mS5 = __builtin_amdgcn_ds_bpermute(ga, s.mS5);
        }
    }
}

template<int J> __device__ __forceinline__ void evenL(Dec& s, int h) {
    constexpr int t = __builtin_ctz(J);   // J even, 2..30 -> t in 1..4
    if constexpr (t == 4) { g5l16(s); f4(s); s.mS3 = s.pos; }
    if constexpr (t == 3) { g4l<J>(s); }
    if constexpr (t >= 3) { f3r(s); }
    if constexpr (t == 2) { g3rl<J>(s); }
    if constexpr (t >= 2) { f2(s); }
    if constexpr (t == 1) { g2l<J>(s); }
    const float l0 = cnop(s.R1[0], s.R1[1]);
    leafR<J, 1>(s, l0, h);
}
template<int J> __device__ __forceinline__ void oddL(Dec& s, int h) {
    const int ug = (int)((s.uhCur >> (J - 1)) & 1u);
    const float l0 = ug ? (s.R1[1] - s.R1[0]) : (s.R1[1] + s.R1[0]);
    leafR<J, (J == 31 ? 2 : 1)>(s, l0, h);
}
template<int J> __device__ __forceinline__ void pairs(Dec& s, int h) {
    evenL<J>(s, h);
    oddL<J + 1>(s, h);
    if constexpr (J + 2 <= 30) pairs<J + 2>(s, h);
}

#define RLF(x, J) __uint_as_float((u32)__builtin_amdgcn_readlane(__float_as_int(x), (J)))

__global__ __launch_bounds__(64) void scl_kernel(const float* __restrict__ in,
                                                 float* __restrict__ out) {
    __shared__ float chS[128];
    const int lane = threadIdx.x;
    const int w = lane & 31;
    const int d = lane >> 5;
    const int dbase = lane & 32;

    Dec s;
    s.pos = lane & 15;
    s.q = (lane >> 4) & 1;
    s.gbase = lane & 48;
    s.isUp = (lane & 8) != 0;
    s.upB = (u32)((lane >> 3) & 1);
    s.idx0 = s.q << 3;
    s.A0 = (dbase | (s.q << 3)) << 2;
    s.uhPrev = 0; s.uhCur = 0; s.rF = 0;

    const size_t base = ((size_t)blockIdx.x * 2 + d) * 128;
    const float a1 = -in[base + w],      c1 = -in[base + 64 + w];
    const float a2 = -in[base + 32 + w], c2 = -in[base + 96 + w];
    chS[d * 64 + w] = a1 + c1;            // stage-6 right-subtree llr (u=0 g)
    chS[d * 64 + 32 + w] = a2 + c2;
    __syncthreads();
    #pragma unroll
    for (int k = 0; k < 32; ++k) s.C[k] = chS[d * 64 + s.q + 2 * k];

    // ---- frozen half (leaves 0..63): all paths identical, u == 0; butterfly
    float v1 = cnop(a1, c1), v2 = cnop(a2, c2);
    { const float n1 = cnop(v1, v2); v2 = v1 + v2; v1 = n1; }             // h=32
    { const float o1 = swap16f(v1), o2 = swap16f(v2);                      // h=16
      v1 = (w & 16) ? (o1 + v1) : cnop(v1, o1);
      v2 = (w & 16) ? (o2 + v2) : cnop(v2, o2); }
    { const float o1 = dppf<CTL_XOR8>(v1), o2 = dppf<CTL_XOR8>(v2);        // h=8
      v1 = (w & 8) ? (o1 + v1) : cnop(v1, o1);
      v2 = (w & 8) ? (o2 + v2) : cnop(v2, o2); }
    { const float o1 = SWZF(v1, 0x101F), o2 = SWZF(v2, 0x101F);            // h=4
      v1 = (w & 4) ? (o1 + v1) : cnop(v1, o1);
      v2 = (w & 4) ? (o2 + v2) : cnop(v2, o2); }
    { const float o1 = dppf<CTL_XOR2>(v1), o2 = dppf<CTL_XOR2>(v2);        // h=2
      v1 = (w & 2) ? (o1 + v1) : cnop(v1, o1);
      v2 = (w & 2) ? (o2 + v2) : cnop(v2, o2); }
    { const float o1 = dppf<CTL_XOR1>(v1), o2 = dppf<CTL_XOR1>(v2);        // h=1
      v1 = (w & 1) ? (o1 + v1) : cnop(v1, o1);
      v2 = (w & 1) ? (o2 + v2) : cnop(v2, o2); }
    const float sp1 = fmaxf(-clip30(v1), 0.0f) + log1pf(expf(-fabsf(clip30(v1))));
    const float sp2 = fmaxf(-clip30(v2), 0.0f) + log1pf(expf(-fabsf(clip30(v2))));

    // exact sequential pm accumulation per decoder (reference FP order)
    s.pm = ((s.pos == 0) || (s.pos == 8)) ? 0.0f : LMAX;
    if (lane < 32) {
        #pragma unroll
        for (int j = 0; j < 32; ++j) s.pm += RLF(sp1, j);
        #pragma unroll
        for (int j = 0; j < 32; ++j) s.pm += RLF(sp2, j);
    } else {
        #pragma unroll
        for (int j = 32; j < 64; ++j) s.pm += RLF(sp1, j);
        #pragma unroll
        for (int j = 32; j < 64; ++j) s.pm += RLF(sp2, j);
    }

    // ---- info half: two 32-leaf halves sharing one unrolled body ----
    #pragma unroll 1
    for (int h = 0; h < 2; ++h) {
        if (h == 0) f6(s); else g6p(s);    // half head: leaf 64 / leaf 96
        s.mS5 = s.pos;
        f5(s); s.mS4 = s.pos;
        f4(s); s.mS3 = s.pos;
        f3r(s); f2(s);
        { const float l0 = cnop(s.R1[0], s.R1[1]); leafR<0, 1>(s, l0, h); }
        oddL<1>(s, h);
        pairs<2>(s, h);
        if (h == 0) { s.uhPrev = s.uhCur; s.uhCur = 0; }
    }

    // best path per decoder = rank 0
    const ull m = __ballot(s.rF == 0);
    const int bl = dbase + (int)__builtin_ctz((u32)(m >> dbase));
    const u32 b0 = gub(s.uhPrev, bl << 2);   // info bits 0..31  (leaves 64..95)
    const u32 b1 = gub(s.uhCur, bl << 2);    // info bits 32..63 (leaves 96..127)
    const size_t ob = ((size_t)blockIdx.x * 2 + d) * 64;
    out[ob + w] = (float)((b0 >> w) & 1u);
    out[ob + 32 + w] = (float)((b1 >> w) & 1u);
}

extern "C" void kernel_launch(void* const* d_in, const int* in_sizes, int n_in,
                              void* d_out, int out_size, void* d_ws, size_t ws_size,
                              hipStream_t stream) {
    (void)n_in; (void)out_size; (void)d_ws; (void)ws_size;
    const float* in = (const float*)d_in[0];
    float* out = (float*)d_out;
    const int batch = in_sizes[0] / 128;  // 2048
    scl_kernel<<<dim3(batch / 2), dim3(64), 0, stream>>>(in, out);
}